// Round 1
// baseline (930.786 us; speedup 1.0000x reference)
//
#include <hip/hip_runtime.h>

// ---------------------------------------------------------------------------
// Model_644245095219: attention block (QKV proj + QK-RMSNorm + RoPE + causal
// GQA flash attention + out proj) for B=1, S=2048, H=4096, nH=32, nKV=8, d=128.
// f16 MFMA path. R1: fixed-M flash softmax (no running max; |score|<=sqrt(128)
// by Cauchy-Schwarz after RMSNorm+RoPE), LDS-based P transform instead of 16
// ds_bpermutes, fused QKV projection GEMM.
// ---------------------------------------------------------------------------

typedef __attribute__((ext_vector_type(4))) float    f32x4;
typedef __attribute__((ext_vector_type(8))) _Float16 f16x8;
typedef __attribute__((ext_vector_type(4))) _Float16 f16x4;
typedef __attribute__((ext_vector_type(2))) _Float16 f16x2;

#define AS1 __attribute__((address_space(1)))
#define AS3 __attribute__((address_space(3)))

static __device__ __forceinline__ void gld_lds16(const void* g, void* l) {
  __builtin_amdgcn_global_load_lds((AS1 void*)(g), (AS3 void*)(l), 16, 0, 0);
}

// ---------------- fp32 -> f16 convert (memory-bound) -----------------------
__global__ void f32_to_f16(const float* __restrict__ src,
                           _Float16* __restrict__ dst, int n4) {
  int i = blockIdx.x * blockDim.x + threadIdx.x;
  if (i >= n4) return;
  float4 v = ((const float4*)src)[i];
  f16x4 o = {(_Float16)v.x, (_Float16)v.y, (_Float16)v.z, (_Float16)v.w};
  ((f16x4*)dst)[i] = o;
}

// ---------------- GEMM: C[M,N] = A[M,K] @ B[N,K]^T  (f16 in, f32 out) ------
__global__ __launch_bounds__(256) void gemm_bt(
    const _Float16* __restrict__ A, const _Float16* __restrict__ B,
    float* __restrict__ C, int M, int N, int K) {
  __shared__ _Float16 lA[128 * 32];
  __shared__ _Float16 lB[128 * 32];
  const int tid  = threadIdx.x;
  const int wave = tid >> 6, lane = tid & 63;
  const int quad = lane >> 4, l16 = lane & 15;
  const int wr = wave >> 1, wc = wave & 1;
  const int m0 = blockIdx.y * 128, n0 = blockIdx.x * 128;

  f32x4 acc[4][4];
#pragma unroll
  for (int i = 0; i < 4; i++)
#pragma unroll
    for (int j = 0; j < 4; j++) acc[i][j] = f32x4{0.f, 0.f, 0.f, 0.f};

  for (int k0 = 0; k0 < K; k0 += 32) {
    __syncthreads();
#pragma unroll
    for (int j = 0; j < 2; ++j) {
      int c0 = wave * 128 + j * 64;
      int c  = c0 + lane;
      const _Float16* gA = A + (size_t)(m0 + (c >> 2)) * K + k0 + (c & 3) * 8;
      const _Float16* gB = B + (size_t)(n0 + (c >> 2)) * K + k0 + (c & 3) * 8;
      gld_lds16(gA, &lA[c0 * 8]);
      gld_lds16(gB, &lB[c0 * 8]);
    }
    __builtin_amdgcn_s_waitcnt(0);
    __syncthreads();

    f16x8 af[4], bfr[4];
#pragma unroll
    for (int mi = 0; mi < 4; mi++)
      af[mi] = *(const f16x8*)&lA[(wr * 64 + mi * 16 + l16) * 32 + quad * 8];
#pragma unroll
    for (int ni = 0; ni < 4; ni++)
      bfr[ni] = *(const f16x8*)&lB[(wc * 64 + ni * 16 + l16) * 32 + quad * 8];
#pragma unroll
    for (int mi = 0; mi < 4; mi++)
#pragma unroll
      for (int ni = 0; ni < 4; ni++)
        acc[mi][ni] = __builtin_amdgcn_mfma_f32_16x16x32_f16(
            af[mi], bfr[ni], acc[mi][ni], 0, 0, 0);
  }
#pragma unroll
  for (int mi = 0; mi < 4; mi++) {
    int m = m0 + wr * 64 + mi * 16 + quad * 4;
#pragma unroll
    for (int ni = 0; ni < 4; ni++) {
      int n = n0 + wc * 64 + ni * 16 + l16;
      float* cp = C + (size_t)m * N + n;
#pragma unroll
      for (int r = 0; r < 4; r++) cp[(size_t)r * N] = acc[mi][ni][r];
    }
  }
}

// ---------------- per-head RMSNorm + RoPE, one wave per (s, head) ----------
// raw: [S, row_stride] f32, head block at col_off + h*128 -> out [nh][S][128]
__global__ void norm_rope(const float* __restrict__ raw, int row_stride,
                          int col_off, const float* __restrict__ w,
                          const float* __restrict__ cosb,
                          const float* __restrict__ sinb,
                          const int* __restrict__ pos,
                          _Float16* __restrict__ out, int nh_log2, int S) {
  int gt = blockIdx.x * blockDim.x + threadIdx.x;
  int wid = gt >> 6, lane = gt & 63;
  int h = wid & ((1 << nh_log2) - 1);
  int s = wid >> nh_log2;
  const float* x = raw + (size_t)s * row_stride + col_off + h * 128;
  float2 v = *(const float2*)&x[lane * 2];
  float ss = v.x * v.x + v.y * v.y;
#pragma unroll
  for (int m = 1; m < 64; m <<= 1) ss += __shfl_xor(ss, m);
  float inv = rsqrtf(ss * (1.f / 128.f) + 1e-6f);
  int p = pos[s];
  float n0 = v.x * inv * w[lane * 2];
  float n1 = v.y * inv * w[lane * 2 + 1];
  float p0 = __shfl_xor(n0, 32);
  float p1 = __shfl_xor(n1, 32);
  float r0 = (lane < 32) ? -p0 : p0;
  float r1 = (lane < 32) ? -p1 : p1;
  float c0 = cosb[p * 128 + lane * 2], c1 = cosb[p * 128 + lane * 2 + 1];
  float s0 = sinb[p * 128 + lane * 2], s1 = sinb[p * 128 + lane * 2 + 1];
  f16x2 o;
  o.x = (_Float16)(n0 * c0 + r0 * s0);
  o.y = (_Float16)(n1 * c1 + r1 * s1);
  *(f16x2*)&out[((size_t)h * S + s) * 128 + lane * 2] = o;
}

// ---------------- V transpose+convert: [S,*] f32 cols -> [1024][S] f16 -----
__global__ __launch_bounds__(256) void v_trans(const float* __restrict__ vraw,
                                               int row_stride,
                                               _Float16* __restrict__ vt,
                                               int S) {
  __shared__ _Float16 tile[64][72];
  int s0 = blockIdx.x * 64, c0 = blockIdx.y * 64;
  int t = threadIdx.x;
  int r = t >> 2, cq = (t & 3) * 16;
  const float* src = vraw + (size_t)(s0 + r) * row_stride + c0 + cq;
#pragma unroll
  for (int j = 0; j < 4; j++) {
    float4 v = *(const float4*)&src[j * 4];
    tile[r][cq + j * 4 + 0] = (_Float16)v.x;
    tile[r][cq + j * 4 + 1] = (_Float16)v.y;
    tile[r][cq + j * 4 + 2] = (_Float16)v.z;
    tile[r][cq + j * 4 + 3] = (_Float16)v.w;
  }
  __syncthreads();
  int orow = t >> 2, sq = (t & 3) * 16;
  _Float16* dst = vt + (size_t)(c0 + orow) * S + s0 + sq;
  f16x8 a, b;
#pragma unroll
  for (int j = 0; j < 8; j++) a[j] = tile[sq + j][orow];
#pragma unroll
  for (int j = 0; j < 8; j++) b[j] = tile[sq + 8 + j][orow];
  *(f16x8*)&dst[0] = a;
  *(f16x8*)&dst[8] = b;
}

// ---------------- causal GQA flash attention (fixed-M softmax) -------------
// Qh: [32][S][128] f16, Kh: [8][S][128] f16, Vt: [8][128][S] f16
// Oout: [S][4096] f16. One wave = 16 q rows, K-step 32.
// |score| <= sqrt(128) (RMSNorm gives |q|=|k|=sqrt(128); RoPE is a rotation),
// so exp(s - M) with fixed M=5 never overflows and the row-max P never
// flushes to 0 in f16. No running max => K-tiles independent (ILP), no alpha.
// P transform C-layout -> B-operand via per-wave LDS patch (2 write_b64 +
// 1 read_b128), replacing 16 ds_bpermutes.
__global__ __launch_bounds__(256) void flash_attn(
    const _Float16* __restrict__ Qh, const _Float16* __restrict__ Kh,
    const _Float16* __restrict__ Vt, _Float16* __restrict__ Oout, int S) {
  __shared__ _Float16 plds[4][16][40];  // per-wave private patch, stride 40
  const int h = blockIdx.y;
  const int kvh = h >> 2;  // n_rep = 4
  const int wave = threadIdx.x >> 6, lane = threadIdx.x & 63;
  const int quad = lane >> 4, l16 = lane & 15;
  const int qb = (gridDim.x - 1 - blockIdx.x) * 64;  // heavy blocks first
  const int wq = qb + wave * 16;
  const _Float16* Q = Qh + ((size_t)h * S + wq) * 128;
  const _Float16* K = Kh + (size_t)kvh * S * 128;
  const _Float16* V = Vt + (size_t)kvh * 128 * S;

  f16x8 qf[4];  // B-operand: n=l16 (q row), k = kq*32+quad*8+j
#pragma unroll
  for (int kq = 0; kq < 4; kq++)
    qf[kq] = *(const f16x8*)&Q[(size_t)l16 * 128 + kq * 32 + quad * 8];

  f32x4 o[8];  // O^T acc: d = t*16+quad*4+r, q = l16
#pragma unroll
  for (int t = 0; t < 8; t++) o[t] = f32x4{0.f, 0.f, 0.f, 0.f};
  float l_i = 0.f;
  const int q_row = wq + l16;
  const float scale = 0.08838834764831845f;  // 1/sqrt(128)
  const float M = 5.0f;

  const int ktend = (wq + 15) >> 5;
  for (int kt = 0; kt <= ktend; ++kt) {
    // scores^T: D[kcol][q]; A = K rows (m=kcol), B = Q^T (n=q)
    f32x4 sc[2];
    sc[0] = f32x4{0.f, 0.f, 0.f, 0.f};
    sc[1] = f32x4{0.f, 0.f, 0.f, 0.f};
#pragma unroll
    for (int mt = 0; mt < 2; mt++)
#pragma unroll
      for (int kq = 0; kq < 4; kq++) {
        f16x8 kf = *(const f16x8*)&K[(size_t)(kt * 32 + mt * 16 + l16) * 128 +
                                     kq * 32 + quad * 8];
        sc[mt] =
            __builtin_amdgcn_mfma_f32_16x16x32_f16(kf, qf[kq], sc[mt], 0, 0, 0);
      }
    // p = exp(s*scale - M), causal-masked; this lane: q=q_row fixed,
    // kcol = kt*32 + mt*16 + quad*4 + r
    float p[2][4];
    float rsum = 0.f;
#pragma unroll
    for (int mt = 0; mt < 2; mt++)
#pragma unroll
      for (int r = 0; r < 4; r++) {
        int kcol = kt * 32 + mt * 16 + quad * 4 + r;
        float e = __expf(fmaf(sc[mt][r], scale, -M));
        e = (kcol <= q_row) ? e : 0.f;
        p[mt][r] = e;
        rsum += e;
      }
    rsum += __shfl_xor(rsum, 16);
    rsum += __shfl_xor(rsum, 32);
    l_i += rsum;
    // C-layout -> B-operand layout via per-wave LDS patch ([q][kcol], pad 40)
    f16x4 pk0 = {(_Float16)p[0][0], (_Float16)p[0][1], (_Float16)p[0][2],
                 (_Float16)p[0][3]};
    f16x4 pk1 = {(_Float16)p[1][0], (_Float16)p[1][1], (_Float16)p[1][2],
                 (_Float16)p[1][3]};
    *(f16x4*)&plds[wave][l16][quad * 4] = pk0;
    *(f16x4*)&plds[wave][l16][16 + quad * 4] = pk1;
    f16x8 pf = *(const f16x8*)&plds[wave][l16][quad * 8];
    // PV: O^T += V^T @ P^T ; A = Vt rows (m=d), B = pf (n=q, k=kcol)
#pragma unroll
    for (int t = 0; t < 8; t++) {
      f16x8 vf = *(const f16x8*)&V[(size_t)(t * 16 + l16) * S + kt * 32 +
                                   quad * 8];
      o[t] = __builtin_amdgcn_mfma_f32_16x16x32_f16(vf, pf, o[t], 0, 0, 0);
    }
  }
  float invl = 1.f / l_i;
  _Float16* op = Oout + (size_t)q_row * 4096 + h * 128 + quad * 4;
#pragma unroll
  for (int t = 0; t < 8; t++) {
    f16x4 ov = {(_Float16)(o[t][0] * invl), (_Float16)(o[t][1] * invl),
                (_Float16)(o[t][2] * invl), (_Float16)(o[t][3] * invl)};
    *(f16x4*)&op[t * 16] = ov;
  }
}

// ---------------------------------------------------------------------------
extern "C" void kernel_launch(void* const* d_in, const int* in_sizes, int n_in,
                              void* d_out, int out_size, void* d_ws,
                              size_t ws_size, hipStream_t stream) {
  const int S = 2048, H = 4096, NH = 32, NKV = 8, D = 128;
  const int NQKV = NH * D + 2 * NKV * D;  // 6144
  const float* hs   = (const float*)d_in[0];
  const int*   pos  = (const int*)d_in[1];
  const float* Wq   = (const float*)d_in[2];
  const float* Wk   = (const float*)d_in[3];
  const float* Wv   = (const float*)d_in[4];
  const float* Wo   = (const float*)d_in[5];
  const float* qw   = (const float*)d_in[6];
  const float* kw   = (const float*)d_in[7];
  const float* cosb = (const float*)d_in[8];
  const float* sinb = (const float*)d_in[9];
  float* out = (float*)d_out;

  // workspace layout (bytes); total 142,606,336
  char* ws = (char*)d_ws;
  _Float16* wqkv    = (_Float16*)(ws + 0);          // 50.33 MB [6144][4096]
  _Float16* hid_bf  = (_Float16*)(ws + 50331648);   // 16.78 MB [S][H]
  float*    qkv_raw = (float*)(ws + 67108864);      // 50.33 MB [S][6144] f32
  _Float16* q_bf    = (_Float16*)(ws + 117440512);  // 16.78 MB [32][S][128]
  _Float16* k_bf    = (_Float16*)(ws + 134217728);  //  4.19 MB [8][S][128]
  _Float16* v_t     = (_Float16*)(ws + 138412032);  //  4.19 MB [1024][S]
  _Float16* attn_bf = (_Float16*)(ws + 67108864);   // alias qkv_raw (dead)
  _Float16* wo_bf   = (_Float16*)(ws + 0);          // alias wqkv (dead)

  // fp32 -> f16 converts (QKV weights fused into one [6144][4096] buffer)
  f32_to_f16<<<(S * H / 4 + 255) / 256, 256, 0, stream>>>(hs, hid_bf, S * H / 4);
  f32_to_f16<<<(H * H / 4 + 255) / 256, 256, 0, stream>>>(Wq, wqkv, H * H / 4);
  f32_to_f16<<<(NKV * D * H / 4 + 255) / 256, 256, 0, stream>>>(
      Wk, wqkv + (size_t)H * H, NKV * D * H / 4);
  f32_to_f16<<<(NKV * D * H / 4 + 255) / 256, 256, 0, stream>>>(
      Wv, wqkv + (size_t)(H + NKV * D) * H, NKV * D * H / 4);

  // fused QKV projection: [2048][6144] = hid @ wqkv^T
  gemm_bt<<<dim3(NQKV / 128, S / 128), 256, 0, stream>>>(hid_bf, wqkv, qkv_raw,
                                                         S, NQKV, H);
  // Wo convert into wqkv slot (dead after QKV gemm)
  f32_to_f16<<<(H * H / 4 + 255) / 256, 256, 0, stream>>>(Wo, wo_bf, H * H / 4);

  // per-head RMSNorm + RoPE
  norm_rope<<<S * NH / 4, 256, 0, stream>>>(qkv_raw, NQKV, 0, qw, cosb, sinb,
                                            pos, q_bf, 5, S);
  norm_rope<<<S * NKV / 4, 256, 0, stream>>>(qkv_raw, NQKV, H, kw, cosb, sinb,
                                             pos, k_bf, 3, S);
  v_trans<<<dim3(S / 64, NKV * D / 64), 256, 0, stream>>>(
      qkv_raw + (size_t)(H + NKV * D), NQKV, v_t, S);

  // causal flash attention -> attn_bf [S][4096] f16 (into dead qkv_raw slot)
  flash_attn<<<dim3(S / 64, NH), 256, 0, stream>>>(q_bf, k_bf, v_t, attn_bf, S);

  // output projection -> d_out fp32
  gemm_bt<<<dim3(H / 128, S / 128), 256, 0, stream>>>(attn_bf, wo_bf, out, S, H,
                                                      H);
}

// Round 2
// 719.759 us; speedup vs baseline: 1.2932x; 1.2932x over previous
//
#include <hip/hip_runtime.h>

// ---------------------------------------------------------------------------
// Model_644245095219: attention block (QKV proj + QK-RMSNorm + RoPE + causal
// GQA flash attention + out proj) for B=1, S=2048, H=4096, nH=32, nKV=8, d=128.
// f16 MFMA path. R1: fixed-M flash softmax (no running max; |score|<=sqrt(128)
// by Cauchy-Schwarz after RMSNorm+RoPE), LDS-based P transform, fused QKV GEMM.
// R2: flash_attn rewritten latency-first: 32 q-rows/wave (2 q-subtiles),
// cross-iteration K prefetch + in-iteration V prefetch, 512 co-resident
// blocks (one grid round), __launch_bounds__(256,2).
// ---------------------------------------------------------------------------

typedef __attribute__((ext_vector_type(4))) float    f32x4;
typedef __attribute__((ext_vector_type(8))) _Float16 f16x8;
typedef __attribute__((ext_vector_type(4))) _Float16 f16x4;
typedef __attribute__((ext_vector_type(2))) _Float16 f16x2;

#define AS1 __attribute__((address_space(1)))
#define AS3 __attribute__((address_space(3)))

static __device__ __forceinline__ void gld_lds16(const void* g, void* l) {
  __builtin_amdgcn_global_load_lds((AS1 void*)(g), (AS3 void*)(l), 16, 0, 0);
}

// ---------------- fp32 -> f16 convert (memory-bound) -----------------------
__global__ void f32_to_f16(const float* __restrict__ src,
                           _Float16* __restrict__ dst, int n4) {
  int i = blockIdx.x * blockDim.x + threadIdx.x;
  if (i >= n4) return;
  float4 v = ((const float4*)src)[i];
  f16x4 o = {(_Float16)v.x, (_Float16)v.y, (_Float16)v.z, (_Float16)v.w};
  ((f16x4*)dst)[i] = o;
}

// ---------------- GEMM: C[M,N] = A[M,K] @ B[N,K]^T  (f16 in, f32 out) ------
__global__ __launch_bounds__(256) void gemm_bt(
    const _Float16* __restrict__ A, const _Float16* __restrict__ B,
    float* __restrict__ C, int M, int N, int K) {
  __shared__ _Float16 lA[128 * 32];
  __shared__ _Float16 lB[128 * 32];
  const int tid  = threadIdx.x;
  const int wave = tid >> 6, lane = tid & 63;
  const int quad = lane >> 4, l16 = lane & 15;
  const int wr = wave >> 1, wc = wave & 1;
  const int m0 = blockIdx.y * 128, n0 = blockIdx.x * 128;

  f32x4 acc[4][4];
#pragma unroll
  for (int i = 0; i < 4; i++)
#pragma unroll
    for (int j = 0; j < 4; j++) acc[i][j] = f32x4{0.f, 0.f, 0.f, 0.f};

  for (int k0 = 0; k0 < K; k0 += 32) {
    __syncthreads();
#pragma unroll
    for (int j = 0; j < 2; ++j) {
      int c0 = wave * 128 + j * 64;
      int c  = c0 + lane;
      const _Float16* gA = A + (size_t)(m0 + (c >> 2)) * K + k0 + (c & 3) * 8;
      const _Float16* gB = B + (size_t)(n0 + (c >> 2)) * K + k0 + (c & 3) * 8;
      gld_lds16(gA, &lA[c0 * 8]);
      gld_lds16(gB, &lB[c0 * 8]);
    }
    __builtin_amdgcn_s_waitcnt(0);
    __syncthreads();

    f16x8 af[4], bfr[4];
#pragma unroll
    for (int mi = 0; mi < 4; mi++)
      af[mi] = *(const f16x8*)&lA[(wr * 64 + mi * 16 + l16) * 32 + quad * 8];
#pragma unroll
    for (int ni = 0; ni < 4; ni++)
      bfr[ni] = *(const f16x8*)&lB[(wc * 64 + ni * 16 + l16) * 32 + quad * 8];
#pragma unroll
    for (int mi = 0; mi < 4; mi++)
#pragma unroll
      for (int ni = 0; ni < 4; ni++)
        acc[mi][ni] = __builtin_amdgcn_mfma_f32_16x16x32_f16(
            af[mi], bfr[ni], acc[mi][ni], 0, 0, 0);
  }
#pragma unroll
  for (int mi = 0; mi < 4; mi++) {
    int m = m0 + wr * 64 + mi * 16 + quad * 4;
#pragma unroll
    for (int ni = 0; ni < 4; ni++) {
      int n = n0 + wc * 64 + ni * 16 + l16;
      float* cp = C + (size_t)m * N + n;
#pragma unroll
      for (int r = 0; r < 4; r++) cp[(size_t)r * N] = acc[mi][ni][r];
    }
  }
}

// ---------------- per-head RMSNorm + RoPE, one wave per (s, head) ----------
// raw: [S, row_stride] f32, head block at col_off + h*128 -> out [nh][S][128]
__global__ void norm_rope(const float* __restrict__ raw, int row_stride,
                          int col_off, const float* __restrict__ w,
                          const float* __restrict__ cosb,
                          const float* __restrict__ sinb,
                          const int* __restrict__ pos,
                          _Float16* __restrict__ out, int nh_log2, int S) {
  int gt = blockIdx.x * blockDim.x + threadIdx.x;
  int wid = gt >> 6, lane = gt & 63;
  int h = wid & ((1 << nh_log2) - 1);
  int s = wid >> nh_log2;
  const float* x = raw + (size_t)s * row_stride + col_off + h * 128;
  float2 v = *(const float2*)&x[lane * 2];
  float ss = v.x * v.x + v.y * v.y;
#pragma unroll
  for (int m = 1; m < 64; m <<= 1) ss += __shfl_xor(ss, m);
  float inv = rsqrtf(ss * (1.f / 128.f) + 1e-6f);
  int p = pos[s];
  float n0 = v.x * inv * w[lane * 2];
  float n1 = v.y * inv * w[lane * 2 + 1];
  float p0 = __shfl_xor(n0, 32);
  float p1 = __shfl_xor(n1, 32);
  float r0 = (lane < 32) ? -p0 : p0;
  float r1 = (lane < 32) ? -p1 : p1;
  float c0 = cosb[p * 128 + lane * 2], c1 = cosb[p * 128 + lane * 2 + 1];
  float s0 = sinb[p * 128 + lane * 2], s1 = sinb[p * 128 + lane * 2 + 1];
  f16x2 o;
  o.x = (_Float16)(n0 * c0 + r0 * s0);
  o.y = (_Float16)(n1 * c1 + r1 * s1);
  *(f16x2*)&out[((size_t)h * S + s) * 128 + lane * 2] = o;
}

// ---------------- V transpose+convert: [S,*] f32 cols -> [1024][S] f16 -----
__global__ __launch_bounds__(256) void v_trans(const float* __restrict__ vraw,
                                               int row_stride,
                                               _Float16* __restrict__ vt,
                                               int S) {
  __shared__ _Float16 tile[64][72];
  int s0 = blockIdx.x * 64, c0 = blockIdx.y * 64;
  int t = threadIdx.x;
  int r = t >> 2, cq = (t & 3) * 16;
  const float* src = vraw + (size_t)(s0 + r) * row_stride + c0 + cq;
#pragma unroll
  for (int j = 0; j < 4; j++) {
    float4 v = *(const float4*)&src[j * 4];
    tile[r][cq + j * 4 + 0] = (_Float16)v.x;
    tile[r][cq + j * 4 + 1] = (_Float16)v.y;
    tile[r][cq + j * 4 + 2] = (_Float16)v.z;
    tile[r][cq + j * 4 + 3] = (_Float16)v.w;
  }
  __syncthreads();
  int orow = t >> 2, sq = (t & 3) * 16;
  _Float16* dst = vt + (size_t)(c0 + orow) * S + s0 + sq;
  f16x8 a, b;
#pragma unroll
  for (int j = 0; j < 8; j++) a[j] = tile[sq + j][orow];
#pragma unroll
  for (int j = 0; j < 8; j++) b[j] = tile[sq + 8 + j][orow];
  *(f16x8*)&dst[0] = a;
  *(f16x8*)&dst[8] = b;
}

// ---------------- causal GQA flash attention (fixed-M softmax) -------------
// Qh: [32][S][128] f16, Kh: [8][S][128] f16, Vt: [8][128][S] f16
// Oout: [S][4096] f16. One wave = 32 q rows (2 q-subtiles of 16), K-step 32.
// |score| <= sqrt(128) (RMSNorm gives |q|=|k|=sqrt(128); RoPE is a rotation),
// so exp(s - M) with fixed M=5 never overflows and the row-max P never
// flushes to 0 in f16. No running max => K-tiles independent (ILP), no alpha.
// Pipelining: V tile issued at iteration top (consumed after softmax, ~300cy
// later); next K tile issued right after QK MFMAs consume current one
// (consumed ~400cy later). All 512 blocks co-resident (1 grid round).
__global__ __launch_bounds__(256, 2) void flash_attn(
    const _Float16* __restrict__ Qh, const _Float16* __restrict__ Kh,
    const _Float16* __restrict__ Vt, _Float16* __restrict__ Oout, int S) {
  __shared__ _Float16 plds[4][2][16][40];  // per-wave patch, stride 40
  const int h = blockIdx.y;
  const int kvh = h >> 2;  // n_rep = 4
  const int wave = threadIdx.x >> 6, lane = threadIdx.x & 63;
  const int quad = lane >> 4, l16 = lane & 15;
  const int qb = (gridDim.x - 1 - blockIdx.x) * 128;  // heavy blocks first
  const int wq = qb + wave * 32;
  const _Float16* Q = Qh + ((size_t)h * S + wq) * 128;
  const _Float16* K = Kh + (size_t)kvh * S * 128;
  const _Float16* V = Vt + (size_t)kvh * 128 * S;

  // Q fragments (B-operand): n = l16 (q row within subtile), k = kq*32+quad*8+j
  f16x8 qf[2][4];
#pragma unroll
  for (int jq = 0; jq < 2; jq++)
#pragma unroll
    for (int kq = 0; kq < 4; kq++)
      qf[jq][kq] =
          *(const f16x8*)&Q[(size_t)(jq * 16 + l16) * 128 + kq * 32 + quad * 8];

  // O^T acc: d = t*16+quad*4+r, q = wq + jq*16 + l16
  f32x4 o[8][2];
#pragma unroll
  for (int t = 0; t < 8; t++)
#pragma unroll
    for (int jq = 0; jq < 2; jq++) o[t][jq] = f32x4{0.f, 0.f, 0.f, 0.f};
  float l_i[2] = {0.f, 0.f};
  const float scale = 0.08838834764831845f;  // 1/sqrt(128)
  const float Mc = 5.0f;

  const int ktend = (wq + 31) >> 5;

  // prologue: K tile 0 into registers
  f16x8 kf[2][4];
#pragma unroll
  for (int mt = 0; mt < 2; mt++)
#pragma unroll
    for (int kq = 0; kq < 4; kq++)
      kf[mt][kq] =
          *(const f16x8*)&K[(size_t)(mt * 16 + l16) * 128 + kq * 32 + quad * 8];

  for (int kt = 0; kt <= ktend; ++kt) {
    // V tile for this kt: issued early, consumed only after softmax
    f16x8 vf[8];
#pragma unroll
    for (int t = 0; t < 8; t++)
      vf[t] = *(const f16x8*)&V[(size_t)(t * 16 + l16) * S + kt * 32 + quad * 8];

    // scores^T: D[kcol][q]; A = K rows (m=kcol), B = Q^T (n=q)
    f32x4 sc[2][2];
#pragma unroll
    for (int mt = 0; mt < 2; mt++)
#pragma unroll
      for (int jq = 0; jq < 2; jq++) sc[mt][jq] = f32x4{0.f, 0.f, 0.f, 0.f};
#pragma unroll
    for (int mt = 0; mt < 2; mt++)
#pragma unroll
      for (int kq = 0; kq < 4; kq++) {
        f16x8 kv = kf[mt][kq];
#pragma unroll
        for (int jq = 0; jq < 2; jq++)
          sc[mt][jq] = __builtin_amdgcn_mfma_f32_16x16x32_f16(kv, qf[jq][kq],
                                                              sc[mt][jq], 0, 0, 0);
      }

    // prefetch next K tile (clamped; redundant reload on last iter)
    {
      int ktn = (kt < ktend) ? kt + 1 : kt;
#pragma unroll
      for (int mt = 0; mt < 2; mt++)
#pragma unroll
        for (int kq = 0; kq < 4; kq++)
          kf[mt][kq] = *(const f16x8*)&K[(size_t)(ktn * 32 + mt * 16 + l16) * 128 +
                                         kq * 32 + quad * 8];
    }

    // p = exp(s*scale - M), causal-masked; lane: q = wq+jq*16+l16,
    // kcol = kt*32 + mt*16 + quad*4 + r
    f16x4 pk[2][2];  // [jq][mt]
#pragma unroll
    for (int jq = 0; jq < 2; jq++) {
      const int q_row = wq + jq * 16 + l16;
      float rsum = 0.f;
#pragma unroll
      for (int mt = 0; mt < 2; mt++) {
        float e0, e1, e2, e3;
        {
          int kc = kt * 32 + mt * 16 + quad * 4;
          e0 = __expf(fmaf(sc[mt][jq][0], scale, -Mc));
          e1 = __expf(fmaf(sc[mt][jq][1], scale, -Mc));
          e2 = __expf(fmaf(sc[mt][jq][2], scale, -Mc));
          e3 = __expf(fmaf(sc[mt][jq][3], scale, -Mc));
          e0 = (kc + 0 <= q_row) ? e0 : 0.f;
          e1 = (kc + 1 <= q_row) ? e1 : 0.f;
          e2 = (kc + 2 <= q_row) ? e2 : 0.f;
          e3 = (kc + 3 <= q_row) ? e3 : 0.f;
        }
        rsum += (e0 + e1) + (e2 + e3);
        pk[jq][mt] = f16x4{(_Float16)e0, (_Float16)e1, (_Float16)e2,
                           (_Float16)e3};
      }
      rsum += __shfl_xor(rsum, 16);
      rsum += __shfl_xor(rsum, 32);
      l_i[jq] += rsum;
    }

    // C-layout -> B-operand layout via per-wave LDS patch ([q][kcol], pad 40)
#pragma unroll
    for (int jq = 0; jq < 2; jq++) {
      *(f16x4*)&plds[wave][jq][l16][quad * 4] = pk[jq][0];
      *(f16x4*)&plds[wave][jq][l16][16 + quad * 4] = pk[jq][1];
    }
    f16x8 pf[2];
#pragma unroll
    for (int jq = 0; jq < 2; jq++)
      pf[jq] = *(const f16x8*)&plds[wave][jq][l16][quad * 8];

    // PV: O^T += V^T @ P^T ; A = Vt rows (m=d), B = pf (n=q, k=kcol)
#pragma unroll
    for (int t = 0; t < 8; t++)
#pragma unroll
      for (int jq = 0; jq < 2; jq++)
        o[t][jq] =
            __builtin_amdgcn_mfma_f32_16x16x32_f16(vf[t], pf[jq], o[t][jq], 0, 0, 0);
  }

#pragma unroll
  for (int jq = 0; jq < 2; jq++) {
    const float invl = 1.f / l_i[jq];
    const int q_row = wq + jq * 16 + l16;
    _Float16* op = Oout + (size_t)q_row * 4096 + h * 128 + quad * 4;
#pragma unroll
    for (int t = 0; t < 8; t++) {
      f16x4 ov = {(_Float16)(o[t][jq][0] * invl), (_Float16)(o[t][jq][1] * invl),
                  (_Float16)(o[t][jq][2] * invl), (_Float16)(o[t][jq][3] * invl)};
      *(f16x4*)&op[t * 16] = ov;
    }
  }
}

// ---------------------------------------------------------------------------
extern "C" void kernel_launch(void* const* d_in, const int* in_sizes, int n_in,
                              void* d_out, int out_size, void* d_ws,
                              size_t ws_size, hipStream_t stream) {
  const int S = 2048, H = 4096, NH = 32, NKV = 8, D = 128;
  const int NQKV = NH * D + 2 * NKV * D;  // 6144
  const float* hs   = (const float*)d_in[0];
  const int*   pos  = (const int*)d_in[1];
  const float* Wq   = (const float*)d_in[2];
  const float* Wk   = (const float*)d_in[3];
  const float* Wv   = (const float*)d_in[4];
  const float* Wo   = (const float*)d_in[5];
  const float* qw   = (const float*)d_in[6];
  const float* kw   = (const float*)d_in[7];
  const float* cosb = (const float*)d_in[8];
  const float* sinb = (const float*)d_in[9];
  float* out = (float*)d_out;

  // workspace layout (bytes); total 142,606,336
  char* ws = (char*)d_ws;
  _Float16* wqkv    = (_Float16*)(ws + 0);          // 50.33 MB [6144][4096]
  _Float16* hid_bf  = (_Float16*)(ws + 50331648);   // 16.78 MB [S][H]
  float*    qkv_raw = (float*)(ws + 67108864);      // 50.33 MB [S][6144] f32
  _Float16* q_bf    = (_Float16*)(ws + 117440512);  // 16.78 MB [32][S][128]
  _Float16* k_bf    = (_Float16*)(ws + 134217728);  //  4.19 MB [8][S][128]
  _Float16* v_t     = (_Float16*)(ws + 138412032);  //  4.19 MB [1024][S]
  _Float16* attn_bf = (_Float16*)(ws + 67108864);   // alias qkv_raw (dead)
  _Float16* wo_bf   = (_Float16*)(ws + 0);          // alias wqkv (dead)

  // fp32 -> f16 converts (QKV weights fused into one [6144][4096] buffer)
  f32_to_f16<<<(S * H / 4 + 255) / 256, 256, 0, stream>>>(hs, hid_bf, S * H / 4);
  f32_to_f16<<<(H * H / 4 + 255) / 256, 256, 0, stream>>>(Wq, wqkv, H * H / 4);
  f32_to_f16<<<(NKV * D * H / 4 + 255) / 256, 256, 0, stream>>>(
      Wk, wqkv + (size_t)H * H, NKV * D * H / 4);
  f32_to_f16<<<(NKV * D * H / 4 + 255) / 256, 256, 0, stream>>>(
      Wv, wqkv + (size_t)(H + NKV * D) * H, NKV * D * H / 4);

  // fused QKV projection: [2048][6144] = hid @ wqkv^T
  gemm_bt<<<dim3(NQKV / 128, S / 128), 256, 0, stream>>>(hid_bf, wqkv, qkv_raw,
                                                         S, NQKV, H);
  // Wo convert into wqkv slot (dead after QKV gemm)
  f32_to_f16<<<(H * H / 4 + 255) / 256, 256, 0, stream>>>(Wo, wo_bf, H * H / 4);

  // per-head RMSNorm + RoPE
  norm_rope<<<S * NH / 4, 256, 0, stream>>>(qkv_raw, NQKV, 0, qw, cosb, sinb,
                                            pos, q_bf, 5, S);
  norm_rope<<<S * NKV / 4, 256, 0, stream>>>(qkv_raw, NQKV, H, kw, cosb, sinb,
                                             pos, k_bf, 3, S);
  v_trans<<<dim3(S / 64, NKV * D / 64), 256, 0, stream>>>(
      qkv_raw + (size_t)(H + NKV * D), NQKV, v_t, S);

  // causal flash attention -> attn_bf [S][4096] f16 (into dead qkv_raw slot)
  flash_attn<<<dim3(S / 128, NH), 256, 0, stream>>>(q_bf, k_bf, v_t, attn_bf, S);

  // output projection -> d_out fp32
  gemm_bt<<<dim3(H / 128, S / 128), 256, 0, stream>>>(attn_bf, wo_bf, out, S, H,
                                                      H);
}

// Round 3
// 558.016 us; speedup vs baseline: 1.6680x; 1.2899x over previous
//
#include <hip/hip_runtime.h>

// ---------------------------------------------------------------------------
// Model_644245095219: attention block (QKV proj + QK-RMSNorm + RoPE + causal
// GQA flash attention + out proj) for B=1, S=2048, H=4096, nH=32, nKV=8, d=128.
// f16 MFMA path. R1: fixed-M flash softmax (no running max; |score|<=sqrt(128)
// by Cauchy-Schwarz after RMSNorm+RoPE), LDS-based P transform, fused QKV GEMM.
// R3: flash_attn: block-cooperative double-buffered LDS staging of K/V tiles
// (global_load_lds w=16, XOR-swizzled via pre-swizzled global source),
// causal pairing (tile i with 31-i) for uniform block work (68 kt-iters),
// XCD-aware block remap so each kv-head group is L2-resident.
// ---------------------------------------------------------------------------

typedef __attribute__((ext_vector_type(4))) float    f32x4;
typedef __attribute__((ext_vector_type(8))) _Float16 f16x8;
typedef __attribute__((ext_vector_type(4))) _Float16 f16x4;
typedef __attribute__((ext_vector_type(2))) _Float16 f16x2;

#define AS1 __attribute__((address_space(1)))
#define AS3 __attribute__((address_space(3)))

static __device__ __forceinline__ void gld_lds16(const void* g, void* l) {
  __builtin_amdgcn_global_load_lds((AS1 void*)(g), (AS3 void*)(l), 16, 0, 0);
}

// ---------------- fp32 -> f16 convert (memory-bound) -----------------------
__global__ void f32_to_f16(const float* __restrict__ src,
                           _Float16* __restrict__ dst, int n4) {
  int i = blockIdx.x * blockDim.x + threadIdx.x;
  if (i >= n4) return;
  float4 v = ((const float4*)src)[i];
  f16x4 o = {(_Float16)v.x, (_Float16)v.y, (_Float16)v.z, (_Float16)v.w};
  ((f16x4*)dst)[i] = o;
}

// ---------------- GEMM: C[M,N] = A[M,K] @ B[N,K]^T  (f16 in, f32 out) ------
__global__ __launch_bounds__(256) void gemm_bt(
    const _Float16* __restrict__ A, const _Float16* __restrict__ B,
    float* __restrict__ C, int M, int N, int K) {
  __shared__ _Float16 lA[128 * 32];
  __shared__ _Float16 lB[128 * 32];
  const int tid  = threadIdx.x;
  const int wave = tid >> 6, lane = tid & 63;
  const int quad = lane >> 4, l16 = lane & 15;
  const int wr = wave >> 1, wc = wave & 1;
  const int m0 = blockIdx.y * 128, n0 = blockIdx.x * 128;

  f32x4 acc[4][4];
#pragma unroll
  for (int i = 0; i < 4; i++)
#pragma unroll
    for (int j = 0; j < 4; j++) acc[i][j] = f32x4{0.f, 0.f, 0.f, 0.f};

  for (int k0 = 0; k0 < K; k0 += 32) {
    __syncthreads();
#pragma unroll
    for (int j = 0; j < 2; ++j) {
      int c0 = wave * 128 + j * 64;
      int c  = c0 + lane;
      const _Float16* gA = A + (size_t)(m0 + (c >> 2)) * K + k0 + (c & 3) * 8;
      const _Float16* gB = B + (size_t)(n0 + (c >> 2)) * K + k0 + (c & 3) * 8;
      gld_lds16(gA, &lA[c0 * 8]);
      gld_lds16(gB, &lB[c0 * 8]);
    }
    __builtin_amdgcn_s_waitcnt(0);
    __syncthreads();

    f16x8 af[4], bfr[4];
#pragma unroll
    for (int mi = 0; mi < 4; mi++)
      af[mi] = *(const f16x8*)&lA[(wr * 64 + mi * 16 + l16) * 32 + quad * 8];
#pragma unroll
    for (int ni = 0; ni < 4; ni++)
      bfr[ni] = *(const f16x8*)&lB[(wc * 64 + ni * 16 + l16) * 32 + quad * 8];
#pragma unroll
    for (int mi = 0; mi < 4; mi++)
#pragma unroll
      for (int ni = 0; ni < 4; ni++)
        acc[mi][ni] = __builtin_amdgcn_mfma_f32_16x16x32_f16(
            af[mi], bfr[ni], acc[mi][ni], 0, 0, 0);
  }
#pragma unroll
  for (int mi = 0; mi < 4; mi++) {
    int m = m0 + wr * 64 + mi * 16 + quad * 4;
#pragma unroll
    for (int ni = 0; ni < 4; ni++) {
      int n = n0 + wc * 64 + ni * 16 + l16;
      float* cp = C + (size_t)m * N + n;
#pragma unroll
      for (int r = 0; r < 4; r++) cp[(size_t)r * N] = acc[mi][ni][r];
    }
  }
}

// ---------------- per-head RMSNorm + RoPE, one wave per (s, head) ----------
__global__ void norm_rope(const float* __restrict__ raw, int row_stride,
                          int col_off, const float* __restrict__ w,
                          const float* __restrict__ cosb,
                          const float* __restrict__ sinb,
                          const int* __restrict__ pos,
                          _Float16* __restrict__ out, int nh_log2, int S) {
  int gt = blockIdx.x * blockDim.x + threadIdx.x;
  int wid = gt >> 6, lane = gt & 63;
  int h = wid & ((1 << nh_log2) - 1);
  int s = wid >> nh_log2;
  const float* x = raw + (size_t)s * row_stride + col_off + h * 128;
  float2 v = *(const float2*)&x[lane * 2];
  float ss = v.x * v.x + v.y * v.y;
#pragma unroll
  for (int m = 1; m < 64; m <<= 1) ss += __shfl_xor(ss, m);
  float inv = rsqrtf(ss * (1.f / 128.f) + 1e-6f);
  int p = pos[s];
  float n0 = v.x * inv * w[lane * 2];
  float n1 = v.y * inv * w[lane * 2 + 1];
  float p0 = __shfl_xor(n0, 32);
  float p1 = __shfl_xor(n1, 32);
  float r0 = (lane < 32) ? -p0 : p0;
  float r1 = (lane < 32) ? -p1 : p1;
  float c0 = cosb[p * 128 + lane * 2], c1 = cosb[p * 128 + lane * 2 + 1];
  float s0 = sinb[p * 128 + lane * 2], s1 = sinb[p * 128 + lane * 2 + 1];
  f16x2 o;
  o.x = (_Float16)(n0 * c0 + r0 * s0);
  o.y = (_Float16)(n1 * c1 + r1 * s1);
  *(f16x2*)&out[((size_t)h * S + s) * 128 + lane * 2] = o;
}

// ---------------- V transpose+convert: [S,*] f32 cols -> [1024][S] f16 -----
__global__ __launch_bounds__(256) void v_trans(const float* __restrict__ vraw,
                                               int row_stride,
                                               _Float16* __restrict__ vt,
                                               int S) {
  __shared__ _Float16 tile[64][72];
  int s0 = blockIdx.x * 64, c0 = blockIdx.y * 64;
  int t = threadIdx.x;
  int r = t >> 2, cq = (t & 3) * 16;
  const float* src = vraw + (size_t)(s0 + r) * row_stride + c0 + cq;
#pragma unroll
  for (int j = 0; j < 4; j++) {
    float4 v = *(const float4*)&src[j * 4];
    tile[r][cq + j * 4 + 0] = (_Float16)v.x;
    tile[r][cq + j * 4 + 1] = (_Float16)v.y;
    tile[r][cq + j * 4 + 2] = (_Float16)v.z;
    tile[r][cq + j * 4 + 3] = (_Float16)v.w;
  }
  __syncthreads();
  int orow = t >> 2, sq = (t & 3) * 16;
  _Float16* dst = vt + (size_t)(c0 + orow) * S + s0 + sq;
  f16x8 a, b;
#pragma unroll
  for (int j = 0; j < 8; j++) a[j] = tile[sq + j][orow];
#pragma unroll
  for (int j = 0; j < 8; j++) b[j] = tile[sq + 8 + j][orow];
  *(f16x8*)&dst[0] = a;
  *(f16x8*)&dst[8] = b;
}

// ---------------- causal GQA flash attention (fixed-M softmax) -------------
// Qh: [32][S][128] f16, Kh: [8][S][128] f16, Vt: [8][128][S] f16
// Oout: [S][4096] f16.
// R3 structure: block = 4 waves; wave = 16 q rows; block handles q-tile pair
// (px, 31-px) of 64 rows each -> uniform 68 kt-iterations per block.
// K/V tiles (32 KV cols) staged cooperatively into double-buffered LDS via
// global_load_lds (linear dest, inverse-swizzled global source); reads use
// the same XOR swizzle -> ~2-way conflicts max. 2-phase pipeline:
// stage(kt+1) || compute(kt); vmcnt drain + barrier per tile.
// XCD remap: flat%8 selects kv-head group (4 q-heads, K+V=1MB L2-resident).
__global__ __launch_bounds__(256, 2) void flash_attn(
    const _Float16* __restrict__ Qh, const _Float16* __restrict__ Kh,
    const _Float16* __restrict__ Vt, _Float16* __restrict__ Oout, int S) {
  __shared__ _Float16 lK[2][32 * 128];  // rows=kcol(32), 16 chunks of 8 f16,
                                        // chunk stored at c^(row&7)
  __shared__ _Float16 lV[2][128 * 32];  // rows=d(128), 4 chunks of 8 f16,
                                        // chunk stored at c^((row>>1)&3)
  __shared__ _Float16 plds[4][16][40];  // per-wave P patch, stride 40
  const int wave = threadIdx.x >> 6, lane = threadIdx.x & 63;
  const int quad = lane >> 4, l16 = lane & 15;

  // XCD-aware remap: flat -> (head, pair). flat%8 = kv-group (if round-robin
  // XCD dispatch holds, each XCD sees one kv head's K/V = 1MB, L2-resident).
  const int flat = blockIdx.y * gridDim.x + blockIdx.x;  // 0..511
  const int head = (flat & 7) * 4 + ((flat >> 3) & 3);
  const int px   = flat >> 5;  // 0..15 pair index
  const int kvh  = head >> 2;
  const _Float16* K = Kh + (size_t)kvh * S * 128;
  const _Float16* V = Vt + (size_t)kvh * 128 * S;

  const int ksw = l16 & 7;                   // K read swizzle
  const int vchunk = quad ^ ((l16 >> 1) & 3);  // V read chunk (row-indep.)
  const float scale = 0.08838834764831845f;  // 1/sqrt(128)
  const float Mc = 5.0f;

#pragma unroll
  for (int seg = 0; seg < 2; ++seg) {
    const int tile = seg ? (31 - px) : px;  // q-tile of 64 rows
    const int q0 = tile * 64;
    const int wq = q0 + wave * 16;
    const _Float16* Q = Qh + ((size_t)head * S + wq) * 128;

    f16x8 qf[4];  // B-operand: n=l16 (q row), k = kq*32+quad*8+j
#pragma unroll
    for (int kq = 0; kq < 4; kq++)
      qf[kq] = *(const f16x8*)&Q[(size_t)l16 * 128 + kq * 32 + quad * 8];

    f32x4 o[8];  // O^T acc: d = t*16+quad*4+r, q = l16
#pragma unroll
    for (int t = 0; t < 8; t++) o[t] = f32x4{0.f, 0.f, 0.f, 0.f};
    float l_i = 0.f;
    const int q_row = wq + l16;
    const int ktend = 2 * tile + 1;  // block-uniform

    // prologue: stage kt=0 into buf0 (each wave: 2 K-rows-groups + 2 V)
#pragma unroll
    for (int u = 0; u < 2; ++u) {
      int j = wave * 2 + u;  // 0..7
      int rK = j * 4 + (lane >> 4);
      int cK = (lane & 15) ^ (rK & 7);
      gld_lds16(K + (size_t)rK * 128 + cK * 8, &lK[0][j * 512]);
      int rV = j * 16 + (lane >> 2);
      int cV = (lane & 3) ^ ((rV >> 1) & 3);
      gld_lds16(V + (size_t)rV * S + cV * 8, &lV[0][j * 512]);
    }
    __builtin_amdgcn_s_waitcnt(0);
    __syncthreads();

    int cur = 0;
    for (int kt = 0; kt <= ktend; ++kt) {
      // stage next tile into buf cur^1 (block-uniform condition)
      if (kt < ktend) {
        const int kn = (kt + 1) * 32;
#pragma unroll
        for (int u = 0; u < 2; ++u) {
          int j = wave * 2 + u;
          int rK = j * 4 + (lane >> 4);
          int cK = (lane & 15) ^ (rK & 7);
          gld_lds16(K + (size_t)(kn + rK) * 128 + cK * 8, &lK[cur ^ 1][j * 512]);
          int rV = j * 16 + (lane >> 2);
          int cV = (lane & 3) ^ ((rV >> 1) & 3);
          gld_lds16(V + (size_t)rV * S + kn + cV * 8, &lV[cur ^ 1][j * 512]);
        }
      }
      // compute current tile (wave-uniform skip of fully-masked tiles)
      if (kt * 32 <= wq + 15) {
        // scores^T: D[kcol][q]; A = K rows (m=kcol), B = Q^T (n=q)
        f32x4 sc[2];
        sc[0] = f32x4{0.f, 0.f, 0.f, 0.f};
        sc[1] = f32x4{0.f, 0.f, 0.f, 0.f};
#pragma unroll
        for (int mt = 0; mt < 2; mt++)
#pragma unroll
          for (int kq = 0; kq < 4; kq++) {
            f16x8 kf = *(const f16x8*)&lK[cur][(mt * 16 + l16) * 128 +
                                              (((kq * 4 + quad) ^ ksw) * 8)];
            sc[mt] =
                __builtin_amdgcn_mfma_f32_16x16x32_f16(kf, qf[kq], sc[mt], 0, 0, 0);
          }
        // p = exp(s*scale - M), causal mask; kcol = kt*32+mt*16+quad*4+r
        float p[2][4];
        float rsum = 0.f;
#pragma unroll
        for (int mt = 0; mt < 2; mt++)
#pragma unroll
          for (int r = 0; r < 4; r++) {
            int kcol = kt * 32 + mt * 16 + quad * 4 + r;
            float e = __expf(fmaf(sc[mt][r], scale, -Mc));
            e = (kcol <= q_row) ? e : 0.f;
            p[mt][r] = e;
            rsum += e;
          }
        rsum += __shfl_xor(rsum, 16);
        rsum += __shfl_xor(rsum, 32);
        l_i += rsum;
        // C-layout -> B-operand via per-wave LDS patch
        f16x4 pk0 = {(_Float16)p[0][0], (_Float16)p[0][1], (_Float16)p[0][2],
                     (_Float16)p[0][3]};
        f16x4 pk1 = {(_Float16)p[1][0], (_Float16)p[1][1], (_Float16)p[1][2],
                     (_Float16)p[1][3]};
        *(f16x4*)&plds[wave][l16][quad * 4] = pk0;
        *(f16x4*)&plds[wave][l16][16 + quad * 4] = pk1;
        f16x8 pf = *(const f16x8*)&plds[wave][l16][quad * 8];
        // PV: O^T += V^T @ P^T
#pragma unroll
        for (int t = 0; t < 8; t++) {
          f16x8 vf =
              *(const f16x8*)&lV[cur][(t * 16 + l16) * 32 + vchunk * 8];
          o[t] = __builtin_amdgcn_mfma_f32_16x16x32_f16(vf, pf, o[t], 0, 0, 0);
        }
      }
      __builtin_amdgcn_s_waitcnt(0);
      __syncthreads();
      cur ^= 1;
    }

    // epilogue: normalize + store this segment
    const float invl = 1.f / l_i;
    _Float16* op = Oout + (size_t)q_row * 4096 + head * 128 + quad * 4;
#pragma unroll
    for (int t = 0; t < 8; t++) {
      f16x4 ov = {(_Float16)(o[t][0] * invl), (_Float16)(o[t][1] * invl),
                  (_Float16)(o[t][2] * invl), (_Float16)(o[t][3] * invl)};
      *(f16x4*)&op[t * 16] = ov;
    }
  }
}

// ---------------------------------------------------------------------------
extern "C" void kernel_launch(void* const* d_in, const int* in_sizes, int n_in,
                              void* d_out, int out_size, void* d_ws,
                              size_t ws_size, hipStream_t stream) {
  const int S = 2048, H = 4096, NH = 32, NKV = 8, D = 128;
  const int NQKV = NH * D + 2 * NKV * D;  // 6144
  const float* hs   = (const float*)d_in[0];
  const int*   pos  = (const int*)d_in[1];
  const float* Wq   = (const float*)d_in[2];
  const float* Wk   = (const float*)d_in[3];
  const float* Wv   = (const float*)d_in[4];
  const float* Wo   = (const float*)d_in[5];
  const float* qw   = (const float*)d_in[6];
  const float* kw   = (const float*)d_in[7];
  const float* cosb = (const float*)d_in[8];
  const float* sinb = (const float*)d_in[9];
  float* out = (float*)d_out;

  // workspace layout (bytes); total 142,606,336
  char* ws = (char*)d_ws;
  _Float16* wqkv    = (_Float16*)(ws + 0);          // 50.33 MB [6144][4096]
  _Float16* hid_bf  = (_Float16*)(ws + 50331648);   // 16.78 MB [S][H]
  float*    qkv_raw = (float*)(ws + 67108864);      // 50.33 MB [S][6144] f32
  _Float16* q_bf    = (_Float16*)(ws + 117440512);  // 16.78 MB [32][S][128]
  _Float16* k_bf    = (_Float16*)(ws + 134217728);  //  4.19 MB [8][S][128]
  _Float16* v_t     = (_Float16*)(ws + 138412032);  //  4.19 MB [1024][S]
  _Float16* attn_bf = (_Float16*)(ws + 67108864);   // alias qkv_raw (dead)
  _Float16* wo_bf   = (_Float16*)(ws + 0);          // alias wqkv (dead)

  // fp32 -> f16 converts (QKV weights fused into one [6144][4096] buffer)
  f32_to_f16<<<(S * H / 4 + 255) / 256, 256, 0, stream>>>(hs, hid_bf, S * H / 4);
  f32_to_f16<<<(H * H / 4 + 255) / 256, 256, 0, stream>>>(Wq, wqkv, H * H / 4);
  f32_to_f16<<<(NKV * D * H / 4 + 255) / 256, 256, 0, stream>>>(
      Wk, wqkv + (size_t)H * H, NKV * D * H / 4);
  f32_to_f16<<<(NKV * D * H / 4 + 255) / 256, 256, 0, stream>>>(
      Wv, wqkv + (size_t)(H + NKV * D) * H, NKV * D * H / 4);

  // fused QKV projection: [2048][6144] = hid @ wqkv^T
  gemm_bt<<<dim3(NQKV / 128, S / 128), 256, 0, stream>>>(hid_bf, wqkv, qkv_raw,
                                                         S, NQKV, H);
  // Wo convert into wqkv slot (dead after QKV gemm)
  f32_to_f16<<<(H * H / 4 + 255) / 256, 256, 0, stream>>>(Wo, wo_bf, H * H / 4);

  // per-head RMSNorm + RoPE
  norm_rope<<<S * NH / 4, 256, 0, stream>>>(qkv_raw, NQKV, 0, qw, cosb, sinb,
                                            pos, q_bf, 5, S);
  norm_rope<<<S * NKV / 4, 256, 0, stream>>>(qkv_raw, NQKV, H, kw, cosb, sinb,
                                             pos, k_bf, 3, S);
  v_trans<<<dim3(S / 64, NKV * D / 64), 256, 0, stream>>>(
      qkv_raw + (size_t)(H + NKV * D), NQKV, v_t, S);

  // causal flash attention -> attn_bf [S][4096] f16 (into dead qkv_raw slot)
  flash_attn<<<dim3(16, NH), 256, 0, stream>>>(q_bf, k_bf, v_t, attn_bf, S);

  // output projection -> d_out fp32
  gemm_bt<<<dim3(H / 128, S / 128), 256, 0, stream>>>(attn_bf, wo_bf, out, S, H,
                                                      H);
}

// Round 4
// 528.428 us; speedup vs baseline: 1.7614x; 1.0560x over previous
//
#include <hip/hip_runtime.h>

// ---------------------------------------------------------------------------
// Model_644245095219: attention block (QKV proj + QK-RMSNorm + RoPE + causal
// GQA flash attention + out proj) for B=1, S=2048, H=4096, nH=32, nKV=8, d=128.
// f16 MFMA path.
// R3: flash_attn: block-cooperative double-buffered LDS staging, causal
// pairing, XCD remap.  (~<150us)
// R4: GEMMs rewritten to the 256-row 8-phase template (T2 swizzle + T3/T4
// counted-vmcnt pipeline + T5 setprio): BM=256, BK=64, 8 waves, 2x64KB LDS
// double buffer, A-halves staged 1 tile ahead, B-halves 2 tiles ahead,
// vmcnt(4)/(2) at tile boundary (never 0). BN=256 for QKV (192 blocks),
// BN=128 for out-proj (256 blocks, full chip).
// ---------------------------------------------------------------------------

typedef __attribute__((ext_vector_type(4))) float    f32x4;
typedef __attribute__((ext_vector_type(8))) _Float16 f16x8;
typedef __attribute__((ext_vector_type(4))) _Float16 f16x4;
typedef __attribute__((ext_vector_type(2))) _Float16 f16x2;

#define AS1 __attribute__((address_space(1)))
#define AS3 __attribute__((address_space(3)))

static __device__ __forceinline__ void gld_lds16(const void* g, void* l) {
  __builtin_amdgcn_global_load_lds((AS1 void*)(g), (AS3 void*)(l), 16, 0, 0);
}

static __device__ __forceinline__ void barrier_raw() {
  asm volatile("s_barrier" ::: "memory");
}
#define WAIT_VMCNT(n) asm volatile("s_waitcnt vmcnt(" #n ")" ::: "memory")

// ---------------- fp32 -> f16 convert (memory-bound) -----------------------
__global__ void f32_to_f16(const float* __restrict__ src,
                           _Float16* __restrict__ dst, int n4) {
  int i = blockIdx.x * blockDim.x + threadIdx.x;
  if (i >= n4) return;
  float4 v = ((const float4*)src)[i];
  f16x4 o = {(_Float16)v.x, (_Float16)v.y, (_Float16)v.z, (_Float16)v.w};
  ((f16x4*)dst)[i] = o;
}

// ---------------- GEMM: C[M,N] = A[M,K] @ B[N,K]^T, 8-phase 256-tile -------
// BM=256 fixed, BN template (256 or 128), BK=64, 512 threads = 8 waves
// (2 M-rows x 4 N-cols of 128x(BN/4) each). LDS double-buffered per K-tile.
// Swizzle: 16B chunk c of row r stored at chunk c^(r&7) (inverse-swizzled
// global source + swizzled ds_read; gld_lds dest stays linear — rule 21).
// Staging schedule per tile t (phases 1-4 = quadrant snake (0,0)(0,1)(1,1)(1,0)):
//   ph1: stage (t+1).A0 -> buf^1   [A0 of buf^1 last read at (t-1).ph3]
//   ph2: stage (t+1).A1 -> buf^1
//   ph3: stage (t+2).B0 -> buf     [B halves of buf last read at t.ph2]
//   ph4: stage (t+2).B1 -> buf ; vmcnt(4) => (t+1).A* landed, (t+2).B* fly
// b0 (qn=0 B frags) kept in registers ph1->ph4 (must NOT re-read LDS: the
// region is overwritten by ph3's stage).
template <int BN>
__global__ __launch_bounds__(512, 2) void gemm256(
    const _Float16* __restrict__ A, const _Float16* __restrict__ B,
    float* __restrict__ C, int N, int K) {
  constexpr int NI = BN / 64;  // n-frags per wave (4 or 2)
  constexpr int NB = NI / 2;   // n-frags per quadrant (2 or 1)
  __shared__ _Float16 lA[2][256 * 64];
  __shared__ _Float16 lB[2][BN * 64];
  const int tid = threadIdx.x;
  const int lane = tid & 63;
  const int wid = tid >> 6;
  const int quad = lane >> 4, l16 = lane & 15;
  const int wr = wid >> 2, wc = wid & 3;
  const int bid = blockIdx.x;
  const int m0 = (bid & 7) * 256;  // 8 M-tiles; bid%8 ~ XCD id -> A-panel/L2
  const int n0 = (bid >> 3) * BN;

  const int sr = tid >> 3, sch = tid & 7;  // staging: row-group / 16B chunk
  const int swz = l16 & 7;                 // read-side swizzle

  f32x4 acc[8][NI];
#pragma unroll
  for (int i = 0; i < 8; i++)
#pragma unroll
    for (int j = 0; j < NI; j++) acc[i][j] = f32x4{0.f, 0.f, 0.f, 0.f};

  const int nt = K >> 6;

  auto stageA = [&](int bb, int h, int kt) {
#pragma unroll
    for (int u = 0; u < 2; ++u) {
      int rl = u * 64 + sr;       // 0..127 within half
      int r = h * 128 + rl;       // row in 256-row tile
      int cg = sch ^ (rl & 7);    // pre-swizzled source chunk
      gld_lds16(A + (size_t)(m0 + r) * K + kt * 64 + cg * 8,
                &lA[bb][(size_t)r * 64 + sch * 8]);
    }
  };
  auto stageB = [&](int bb, int h, int kt) {
#pragma unroll
    for (int u = 0; u < 2; ++u) {
      int rl = u * 64 + sr;
      int r = h * 128 + rl;
      int cg = sch ^ (rl & 7);
      gld_lds16(B + (size_t)(n0 + r) * K + kt * 64 + cg * 8,
                &lB[bb][(size_t)r * 64 + sch * 8]);
    }
  };

  auto ldA = [&](f16x8* dst, int qm, int bb) {
#pragma unroll
    for (int mi = 0; mi < 4; ++mi)
#pragma unroll
      for (int kk = 0; kk < 2; ++kk) {
        int row = wr * 128 + (qm * 4 + mi) * 16 + l16;
        int ch = (kk * 4 + quad) ^ swz;
        dst[mi * 2 + kk] = *(const f16x8*)&lA[bb][(size_t)row * 64 + ch * 8];
      }
  };
  auto ldB = [&](f16x8* dst, int qn, int bb) {
#pragma unroll
    for (int ni = 0; ni < NB; ++ni)
#pragma unroll
      for (int kk = 0; kk < 2; ++kk) {
        int row = wc * (BN / 4) + (qn * NB + ni) * 16 + l16;
        int ch = (kk * 4 + quad) ^ swz;
        dst[ni * 2 + kk] = *(const f16x8*)&lB[bb][(size_t)row * 64 + ch * 8];
      }
  };
  auto mmQ = [&](const f16x8* af, const f16x8* bf, int qm, int qn) {
    __builtin_amdgcn_s_setprio(1);
    __builtin_amdgcn_sched_barrier(0);
#pragma unroll
    for (int mi = 0; mi < 4; ++mi)
#pragma unroll
      for (int ni = 0; ni < NB; ++ni)
#pragma unroll
        for (int kk = 0; kk < 2; ++kk)
          acc[qm * 4 + mi][qn * NB + ni] =
              __builtin_amdgcn_mfma_f32_16x16x32_f16(
                  af[mi * 2 + kk], bf[ni * 2 + kk],
                  acc[qm * 4 + mi][qn * NB + ni], 0, 0, 0);
    __builtin_amdgcn_sched_barrier(0);
    __builtin_amdgcn_s_setprio(0);
  };

  // prologue: tile0 all halves + tile1 B halves (steady-state pattern)
  stageA(0, 0, 0);
  stageA(0, 1, 0);
  stageB(0, 0, 0);
  if constexpr (BN == 256) stageB(0, 1, 0);
  stageB(1, 0, 1);
  if constexpr (BN == 256) stageB(1, 1, 1);
  if constexpr (BN == 256) {
    WAIT_VMCNT(4);
  } else {
    WAIT_VMCNT(2);
  }
  barrier_raw();

  f16x8 af[8], b0[2 * NB], b1[2 * NB];
  for (int t = 0; t < nt; ++t) {
    const int b = t & 1;
    const int tn1 = (t + 1 < nt) ? t + 1 : t;  // clamp: uniform counts
    const int tn2 = (t + 2 < nt) ? t + 2 : t;
    // ph1: Q(0,0)
    ldA(af, 0, b);
    ldB(b0, 0, b);
    stageA(b ^ 1, 0, tn1);
    barrier_raw();
    mmQ(af, b0, 0, 0);
    barrier_raw();
    // ph2: Q(0,1)
    ldB(b1, 1, b);
    stageA(b ^ 1, 1, tn1);
    barrier_raw();
    mmQ(af, b1, 0, 1);
    barrier_raw();
    // ph3: Q(1,1)
    ldA(af, 1, b);
    stageB(b, 0, tn2);
    barrier_raw();
    mmQ(af, b1, 1, 1);
    barrier_raw();
    // ph4: Q(1,0)  (b0 from registers)
    if constexpr (BN == 256) stageB(b, 1, tn2);
    if constexpr (BN == 256) {
      WAIT_VMCNT(4);
    } else {
      WAIT_VMCNT(2);
    }
    barrier_raw();
    mmQ(af, b0, 1, 0);
    barrier_raw();
  }

#pragma unroll
  for (int mi8 = 0; mi8 < 8; ++mi8) {
    int m = m0 + wr * 128 + mi8 * 16 + quad * 4;
#pragma unroll
    for (int ni = 0; ni < NI; ++ni) {
      int n = n0 + wc * (BN / 4) + ni * 16 + l16;
      float* cp = C + (size_t)m * N + n;
#pragma unroll
      for (int r = 0; r < 4; ++r) cp[(size_t)r * N] = acc[mi8][ni][r];
    }
  }
}

// ---------------- per-head RMSNorm + RoPE, one wave per (s, head) ----------
__global__ void norm_rope(const float* __restrict__ raw, int row_stride,
                          int col_off, const float* __restrict__ w,
                          const float* __restrict__ cosb,
                          const float* __restrict__ sinb,
                          const int* __restrict__ pos,
                          _Float16* __restrict__ out, int nh_log2, int S) {
  int gt = blockIdx.x * blockDim.x + threadIdx.x;
  int wid = gt >> 6, lane = gt & 63;
  int h = wid & ((1 << nh_log2) - 1);
  int s = wid >> nh_log2;
  const float* x = raw + (size_t)s * row_stride + col_off + h * 128;
  float2 v = *(const float2*)&x[lane * 2];
  float ss = v.x * v.x + v.y * v.y;
#pragma unroll
  for (int m = 1; m < 64; m <<= 1) ss += __shfl_xor(ss, m);
  float inv = rsqrtf(ss * (1.f / 128.f) + 1e-6f);
  int p = pos[s];
  float n0 = v.x * inv * w[lane * 2];
  float n1 = v.y * inv * w[lane * 2 + 1];
  float p0 = __shfl_xor(n0, 32);
  float p1 = __shfl_xor(n1, 32);
  float r0 = (lane < 32) ? -p0 : p0;
  float r1 = (lane < 32) ? -p1 : p1;
  float c0 = cosb[p * 128 + lane * 2], c1 = cosb[p * 128 + lane * 2 + 1];
  float s0 = sinb[p * 128 + lane * 2], s1 = sinb[p * 128 + lane * 2 + 1];
  f16x2 o;
  o.x = (_Float16)(n0 * c0 + r0 * s0);
  o.y = (_Float16)(n1 * c1 + r1 * s1);
  *(f16x2*)&out[((size_t)h * S + s) * 128 + lane * 2] = o;
}

// ---------------- V transpose+convert: [S,*] f32 cols -> [1024][S] f16 -----
__global__ __launch_bounds__(256) void v_trans(const float* __restrict__ vraw,
                                               int row_stride,
                                               _Float16* __restrict__ vt,
                                               int S) {
  __shared__ _Float16 tile[64][72];
  int s0 = blockIdx.x * 64, c0 = blockIdx.y * 64;
  int t = threadIdx.x;
  int r = t >> 2, cq = (t & 3) * 16;
  const float* src = vraw + (size_t)(s0 + r) * row_stride + c0 + cq;
#pragma unroll
  for (int j = 0; j < 4; j++) {
    float4 v = *(const float4*)&src[j * 4];
    tile[r][cq + j * 4 + 0] = (_Float16)v.x;
    tile[r][cq + j * 4 + 1] = (_Float16)v.y;
    tile[r][cq + j * 4 + 2] = (_Float16)v.z;
    tile[r][cq + j * 4 + 3] = (_Float16)v.w;
  }
  __syncthreads();
  int orow = t >> 2, sq = (t & 3) * 16;
  _Float16* dst = vt + (size_t)(c0 + orow) * S + s0 + sq;
  f16x8 a, b;
#pragma unroll
  for (int j = 0; j < 8; j++) a[j] = tile[sq + j][orow];
#pragma unroll
  for (int j = 0; j < 8; j++) b[j] = tile[sq + 8 + j][orow];
  *(f16x8*)&dst[0] = a;
  *(f16x8*)&dst[8] = b;
}

// ---------------- causal GQA flash attention (fixed-M softmax) -------------
// Qh: [32][S][128] f16, Kh: [8][S][128] f16, Vt: [8][128][S] f16
// Oout: [S][4096] f16.
// Block = 4 waves; wave = 16 q rows; block handles q-tile pair (px, 31-px)
// of 64 rows each -> uniform 68 kt-iterations per block. K/V tiles staged
// cooperatively into double-buffered LDS via global_load_lds (linear dest,
// inverse-swizzled global source); reads use the same XOR swizzle.
// 2-phase pipeline: stage(kt+1) || compute(kt); drain + barrier per tile.
__global__ __launch_bounds__(256, 2) void flash_attn(
    const _Float16* __restrict__ Qh, const _Float16* __restrict__ Kh,
    const _Float16* __restrict__ Vt, _Float16* __restrict__ Oout, int S) {
  __shared__ _Float16 lK[2][32 * 128];
  __shared__ _Float16 lV[2][128 * 32];
  __shared__ _Float16 plds[4][16][40];
  const int wave = threadIdx.x >> 6, lane = threadIdx.x & 63;
  const int quad = lane >> 4, l16 = lane & 15;

  const int flat = blockIdx.y * gridDim.x + blockIdx.x;  // 0..511
  const int head = (flat & 7) * 4 + ((flat >> 3) & 3);
  const int px   = flat >> 5;  // 0..15 pair index
  const int kvh  = head >> 2;
  const _Float16* K = Kh + (size_t)kvh * S * 128;
  const _Float16* V = Vt + (size_t)kvh * 128 * S;

  const int ksw = l16 & 7;
  const int vchunk = quad ^ ((l16 >> 1) & 3);
  const float scale = 0.08838834764831845f;  // 1/sqrt(128)
  const float Mc = 5.0f;

#pragma unroll
  for (int seg = 0; seg < 2; ++seg) {
    const int tile = seg ? (31 - px) : px;
    const int q0 = tile * 64;
    const int wq = q0 + wave * 16;
    const _Float16* Q = Qh + ((size_t)head * S + wq) * 128;

    f16x8 qf[4];
#pragma unroll
    for (int kq = 0; kq < 4; kq++)
      qf[kq] = *(const f16x8*)&Q[(size_t)l16 * 128 + kq * 32 + quad * 8];

    f32x4 o[8];
#pragma unroll
    for (int t = 0; t < 8; t++) o[t] = f32x4{0.f, 0.f, 0.f, 0.f};
    float l_i = 0.f;
    const int q_row = wq + l16;
    const int ktend = 2 * tile + 1;

#pragma unroll
    for (int u = 0; u < 2; ++u) {
      int j = wave * 2 + u;
      int rK = j * 4 + (lane >> 4);
      int cK = (lane & 15) ^ (rK & 7);
      gld_lds16(K + (size_t)rK * 128 + cK * 8, &lK[0][j * 512]);
      int rV = j * 16 + (lane >> 2);
      int cV = (lane & 3) ^ ((rV >> 1) & 3);
      gld_lds16(V + (size_t)rV * S + cV * 8, &lV[0][j * 512]);
    }
    __builtin_amdgcn_s_waitcnt(0);
    __syncthreads();

    int cur = 0;
    for (int kt = 0; kt <= ktend; ++kt) {
      if (kt < ktend) {
        const int kn = (kt + 1) * 32;
#pragma unroll
        for (int u = 0; u < 2; ++u) {
          int j = wave * 2 + u;
          int rK = j * 4 + (lane >> 4);
          int cK = (lane & 15) ^ (rK & 7);
          gld_lds16(K + (size_t)(kn + rK) * 128 + cK * 8, &lK[cur ^ 1][j * 512]);
          int rV = j * 16 + (lane >> 2);
          int cV = (lane & 3) ^ ((rV >> 1) & 3);
          gld_lds16(V + (size_t)rV * S + kn + cV * 8, &lV[cur ^ 1][j * 512]);
        }
      }
      if (kt * 32 <= wq + 15) {
        f32x4 sc[2];
        sc[0] = f32x4{0.f, 0.f, 0.f, 0.f};
        sc[1] = f32x4{0.f, 0.f, 0.f, 0.f};
#pragma unroll
        for (int mt = 0; mt < 2; mt++)
#pragma unroll
          for (int kq = 0; kq < 4; kq++) {
            f16x8 kf = *(const f16x8*)&lK[cur][(mt * 16 + l16) * 128 +
                                              (((kq * 4 + quad) ^ ksw) * 8)];
            sc[mt] = __builtin_amdgcn_mfma_f32_16x16x32_f16(kf, qf[kq], sc[mt],
                                                            0, 0, 0);
          }
        float p[2][4];
        float rsum = 0.f;
#pragma unroll
        for (int mt = 0; mt < 2; mt++)
#pragma unroll
          for (int r = 0; r < 4; r++) {
            int kcol = kt * 32 + mt * 16 + quad * 4 + r;
            float e = __expf(fmaf(sc[mt][r], scale, -Mc));
            e = (kcol <= q_row) ? e : 0.f;
            p[mt][r] = e;
            rsum += e;
          }
        rsum += __shfl_xor(rsum, 16);
        rsum += __shfl_xor(rsum, 32);
        l_i += rsum;
        f16x4 pk0 = {(_Float16)p[0][0], (_Float16)p[0][1], (_Float16)p[0][2],
                     (_Float16)p[0][3]};
        f16x4 pk1 = {(_Float16)p[1][0], (_Float16)p[1][1], (_Float16)p[1][2],
                     (_Float16)p[1][3]};
        *(f16x4*)&plds[wave][l16][quad * 4] = pk0;
        *(f16x4*)&plds[wave][l16][16 + quad * 4] = pk1;
        f16x8 pf = *(const f16x8*)&plds[wave][l16][quad * 8];
#pragma unroll
        for (int t = 0; t < 8; t++) {
          f16x8 vf = *(const f16x8*)&lV[cur][(t * 16 + l16) * 32 + vchunk * 8];
          o[t] = __builtin_amdgcn_mfma_f32_16x16x32_f16(vf, pf, o[t], 0, 0, 0);
        }
      }
      __builtin_amdgcn_s_waitcnt(0);
      __syncthreads();
      cur ^= 1;
    }

    const float invl = 1.f / l_i;
    _Float16* op = Oout + (size_t)q_row * 4096 + head * 128 + quad * 4;
#pragma unroll
    for (int t = 0; t < 8; t++) {
      f16x4 ov = {(_Float16)(o[t][0] * invl), (_Float16)(o[t][1] * invl),
                  (_Float16)(o[t][2] * invl), (_Float16)(o[t][3] * invl)};
      *(f16x4*)&op[t * 16] = ov;
    }
  }
}

// ---------------------------------------------------------------------------
extern "C" void kernel_launch(void* const* d_in, const int* in_sizes, int n_in,
                              void* d_out, int out_size, void* d_ws,
                              size_t ws_size, hipStream_t stream) {
  const int S = 2048, H = 4096, NH = 32, NKV = 8, D = 128;
  const int NQKV = NH * D + 2 * NKV * D;  // 6144
  const float* hs   = (const float*)d_in[0];
  const int*   pos  = (const int*)d_in[1];
  const float* Wq   = (const float*)d_in[2];
  const float* Wk   = (const float*)d_in[3];
  const float* Wv   = (const float*)d_in[4];
  const float* Wo   = (const float*)d_in[5];
  const float* qw   = (const float*)d_in[6];
  const float* kw   = (const float*)d_in[7];
  const float* cosb = (const float*)d_in[8];
  const float* sinb = (const float*)d_in[9];
  float* out = (float*)d_out;

  // workspace layout (bytes); total 142,606,336
  char* ws = (char*)d_ws;
  _Float16* wqkv    = (_Float16*)(ws + 0);          // 50.33 MB [6144][4096]
  _Float16* hid_bf  = (_Float16*)(ws + 50331648);   // 16.78 MB [S][H]
  float*    qkv_raw = (float*)(ws + 67108864);      // 50.33 MB [S][6144] f32
  _Float16* q_bf    = (_Float16*)(ws + 117440512);  // 16.78 MB [32][S][128]
  _Float16* k_bf    = (_Float16*)(ws + 134217728);  //  4.19 MB [8][S][128]
  _Float16* v_t     = (_Float16*)(ws + 138412032);  //  4.19 MB [1024][S]
  _Float16* attn_bf = (_Float16*)(ws + 67108864);   // alias qkv_raw (dead)
  _Float16* wo_bf   = (_Float16*)(ws + 0);          // alias wqkv (dead)

  // fp32 -> f16 converts (QKV weights fused into one [6144][4096] buffer)
  f32_to_f16<<<(S * H / 4 + 255) / 256, 256, 0, stream>>>(hs, hid_bf, S * H / 4);
  f32_to_f16<<<(H * H / 4 + 255) / 256, 256, 0, stream>>>(Wq, wqkv, H * H / 4);
  f32_to_f16<<<(NKV * D * H / 4 + 255) / 256, 256, 0, stream>>>(
      Wk, wqkv + (size_t)H * H, NKV * D * H / 4);
  f32_to_f16<<<(NKV * D * H / 4 + 255) / 256, 256, 0, stream>>>(
      Wv, wqkv + (size_t)(H + NKV * D) * H, NKV * D * H / 4);

  // fused QKV projection: [2048][6144] = hid @ wqkv^T  (8-phase, BN=256)
  gemm256<256><<<dim3((NQKV / 256) * 8), 512, 0, stream>>>(hid_bf, wqkv,
                                                           qkv_raw, NQKV, H);
  // Wo convert into wqkv slot (dead after QKV gemm)
  f32_to_f16<<<(H * H / 4 + 255) / 256, 256, 0, stream>>>(Wo, wo_bf, H * H / 4);

  // per-head RMSNorm + RoPE
  norm_rope<<<S * NH / 4, 256, 0, stream>>>(qkv_raw, NQKV, 0, qw, cosb, sinb,
                                            pos, q_bf, 5, S);
  norm_rope<<<S * NKV / 4, 256, 0, stream>>>(qkv_raw, NQKV, H, kw, cosb, sinb,
                                             pos, k_bf, 3, S);
  v_trans<<<dim3(S / 64, NKV * D / 64), 256, 0, stream>>>(
      qkv_raw + (size_t)(H + NKV * D), NQKV, v_t, S);

  // causal flash attention -> attn_bf [S][4096] f16 (into dead qkv_raw slot)
  flash_attn<<<dim3(16, NH), 256, 0, stream>>>(q_bf, k_bf, v_t, attn_bf, S);

  // output projection -> d_out fp32  (8-phase, BN=128: 256 blocks, full chip)
  gemm256<128><<<dim3((H / 128) * 8), 512, 0, stream>>>(attn_bf, wo_bf, out, H,
                                                        H);
}

// Round 5
// 522.540 us; speedup vs baseline: 1.7813x; 1.0113x over previous
//
#include <hip/hip_runtime.h>

// ---------------------------------------------------------------------------
// Model_644245095219: attention block (QKV proj + QK-RMSNorm + RoPE + causal
// GQA flash attention + out proj) for B=1, S=2048, H=4096, nH=32, nKV=8, d=128.
// f16 MFMA path.
// R4: GEMMs on the 256-row 8-phase template (T2 swizzle, counted vmcnt, T5).
// R5: flash_attn 3-deep LDS rotation w/ counted vmcnt(4) (no per-iter full
// drain); QKV GEMM writes f16 directly (norm_rope/v_trans read f16);
// hs/Wq/Wk/Wv converts fused into one kernel.
// ---------------------------------------------------------------------------

typedef __attribute__((ext_vector_type(4))) float    f32x4;
typedef __attribute__((ext_vector_type(8))) _Float16 f16x8;
typedef __attribute__((ext_vector_type(4))) _Float16 f16x4;
typedef __attribute__((ext_vector_type(2))) _Float16 f16x2;

#define AS1 __attribute__((address_space(1)))
#define AS3 __attribute__((address_space(3)))

static __device__ __forceinline__ void gld_lds16(const void* g, void* l) {
  __builtin_amdgcn_global_load_lds((AS1 void*)(g), (AS3 void*)(l), 16, 0, 0);
}

static __device__ __forceinline__ void barrier_raw() {
  asm volatile("s_barrier" ::: "memory");
}
#define WAIT_VMCNT(n) asm volatile("s_waitcnt vmcnt(" #n ")" ::: "memory")

// ---------------- fp32 -> f16 converts -------------------------------------
__global__ void f32_to_f16(const float* __restrict__ src,
                           _Float16* __restrict__ dst, int n4) {
  int i = blockIdx.x * blockDim.x + threadIdx.x;
  if (i >= n4) return;
  float4 v = ((const float4*)src)[i];
  f16x4 o = {(_Float16)v.x, (_Float16)v.y, (_Float16)v.z, (_Float16)v.w};
  ((f16x4*)dst)[i] = o;
}

// fused 4-segment convert (hs, Wq, Wk, Wv) — one launch instead of four
__global__ void cvt4(const float* __restrict__ s0, const float* __restrict__ s1,
                     const float* __restrict__ s2, const float* __restrict__ s3,
                     _Float16* __restrict__ d0, _Float16* __restrict__ d1,
                     _Float16* __restrict__ d2, _Float16* __restrict__ d3,
                     int n0, int n1, int n2, int n3) {
  int i = blockIdx.x * blockDim.x + threadIdx.x;
  const float* s;
  _Float16* d;
  int j = i;
  if (j < n0) {
    s = s0; d = d0;
  } else if ((j -= n0) < n1) {
    s = s1; d = d1;
  } else if ((j -= n1) < n2) {
    s = s2; d = d2;
  } else if ((j -= n2) < n3) {
    s = s3; d = d3;
  } else {
    return;
  }
  float4 v = ((const float4*)s)[j];
  f16x4 o = {(_Float16)v.x, (_Float16)v.y, (_Float16)v.z, (_Float16)v.w};
  ((f16x4*)d)[j] = o;
}

// ---------------- GEMM: C[M,N] = A[M,K] @ B[N,K]^T, 8-phase 256-tile -------
// BM=256 fixed, BN template (256 or 128), BK=64, 512 threads = 8 waves
// (2 M-rows x 4 N-cols). LDS double-buffered per K-tile. Swizzle: 16B chunk c
// of row r stored at chunk c^(r&7) (inverse-swizzled global source +
// swizzled ds_read; gld_lds dest stays linear — rule 21).
// Staging per tile t: ph1 (t+1).A0->buf^1, ph2 (t+1).A1, ph3 (t+2).B0->buf,
// ph4 (t+2).B1; vmcnt(4) at ph4 => (t+1).A landed, (t+2).B in flight.
// b0 (qn=0 B frags) held in registers ph1->ph4 (ph3 overwrites that LDS).
template <int BN, typename CT>
__global__ __launch_bounds__(512, 2) void gemm256(
    const _Float16* __restrict__ A, const _Float16* __restrict__ B,
    CT* __restrict__ C, int N, int K) {
  constexpr int NI = BN / 64;  // n-frags per wave (4 or 2)
  constexpr int NB = NI / 2;   // n-frags per quadrant (2 or 1)
  __shared__ _Float16 lA[2][256 * 64];
  __shared__ _Float16 lB[2][BN * 64];
  const int tid = threadIdx.x;
  const int lane = tid & 63;
  const int wid = tid >> 6;
  const int quad = lane >> 4, l16 = lane & 15;
  const int wr = wid >> 2, wc = wid & 3;
  const int bid = blockIdx.x;
  const int m0 = (bid & 7) * 256;  // 8 M-tiles; bid%8 ~ XCD id -> A-panel/L2
  const int n0 = (bid >> 3) * BN;

  const int sr = tid >> 3, sch = tid & 7;  // staging: row-group / 16B chunk
  const int swz = l16 & 7;                 // read-side swizzle

  f32x4 acc[8][NI];
#pragma unroll
  for (int i = 0; i < 8; i++)
#pragma unroll
    for (int j = 0; j < NI; j++) acc[i][j] = f32x4{0.f, 0.f, 0.f, 0.f};

  const int nt = K >> 6;

  auto stageA = [&](int bb, int h, int kt) {
#pragma unroll
    for (int u = 0; u < 2; ++u) {
      int rl = u * 64 + sr;
      int r = h * 128 + rl;
      int cg = sch ^ (rl & 7);
      gld_lds16(A + (size_t)(m0 + r) * K + kt * 64 + cg * 8,
                &lA[bb][(size_t)r * 64 + sch * 8]);
    }
  };
  auto stageB = [&](int bb, int h, int kt) {
#pragma unroll
    for (int u = 0; u < 2; ++u) {
      int rl = u * 64 + sr;
      int r = h * 128 + rl;
      int cg = sch ^ (rl & 7);
      gld_lds16(B + (size_t)(n0 + r) * K + kt * 64 + cg * 8,
                &lB[bb][(size_t)r * 64 + sch * 8]);
    }
  };

  auto ldA = [&](f16x8* dst, int qm, int bb) {
#pragma unroll
    for (int mi = 0; mi < 4; ++mi)
#pragma unroll
      for (int kk = 0; kk < 2; ++kk) {
        int row = wr * 128 + (qm * 4 + mi) * 16 + l16;
        int ch = (kk * 4 + quad) ^ swz;
        dst[mi * 2 + kk] = *(const f16x8*)&lA[bb][(size_t)row * 64 + ch * 8];
      }
  };
  auto ldB = [&](f16x8* dst, int qn, int bb) {
#pragma unroll
    for (int ni = 0; ni < NB; ++ni)
#pragma unroll
      for (int kk = 0; kk < 2; ++kk) {
        int row = wc * (BN / 4) + (qn * NB + ni) * 16 + l16;
        int ch = (kk * 4 + quad) ^ swz;
        dst[ni * 2 + kk] = *(const f16x8*)&lB[bb][(size_t)row * 64 + ch * 8];
      }
  };
  auto mmQ = [&](const f16x8* af, const f16x8* bf, int qm, int qn) {
    __builtin_amdgcn_s_setprio(1);
    __builtin_amdgcn_sched_barrier(0);
#pragma unroll
    for (int mi = 0; mi < 4; ++mi)
#pragma unroll
      for (int ni = 0; ni < NB; ++ni)
#pragma unroll
        for (int kk = 0; kk < 2; ++kk)
          acc[qm * 4 + mi][qn * NB + ni] =
              __builtin_amdgcn_mfma_f32_16x16x32_f16(
                  af[mi * 2 + kk], bf[ni * 2 + kk],
                  acc[qm * 4 + mi][qn * NB + ni], 0, 0, 0);
    __builtin_amdgcn_sched_barrier(0);
    __builtin_amdgcn_s_setprio(0);
  };

  // prologue: tile0 all halves + tile1 B halves (steady-state pattern)
  stageA(0, 0, 0);
  stageA(0, 1, 0);
  stageB(0, 0, 0);
  if constexpr (BN == 256) stageB(0, 1, 0);
  stageB(1, 0, 1);
  if constexpr (BN == 256) stageB(1, 1, 1);
  if constexpr (BN == 256) {
    WAIT_VMCNT(4);
  } else {
    WAIT_VMCNT(2);
  }
  barrier_raw();

  f16x8 af[8], b0[2 * NB], b1[2 * NB];
  for (int t = 0; t < nt; ++t) {
    const int b = t & 1;
    const int tn1 = (t + 1 < nt) ? t + 1 : t;  // clamp: uniform counts
    const int tn2 = (t + 2 < nt) ? t + 2 : t;
    // ph1: Q(0,0)
    ldA(af, 0, b);
    ldB(b0, 0, b);
    stageA(b ^ 1, 0, tn1);
    barrier_raw();
    mmQ(af, b0, 0, 0);
    barrier_raw();
    // ph2: Q(0,1)
    ldB(b1, 1, b);
    stageA(b ^ 1, 1, tn1);
    barrier_raw();
    mmQ(af, b1, 0, 1);
    barrier_raw();
    // ph3: Q(1,1)
    ldA(af, 1, b);
    stageB(b, 0, tn2);
    barrier_raw();
    mmQ(af, b1, 1, 1);
    barrier_raw();
    // ph4: Q(1,0)  (b0 from registers)
    if constexpr (BN == 256) stageB(b, 1, tn2);
    if constexpr (BN == 256) {
      WAIT_VMCNT(4);
    } else {
      WAIT_VMCNT(2);
    }
    barrier_raw();
    mmQ(af, b0, 1, 0);
    barrier_raw();
  }

#pragma unroll
  for (int mi8 = 0; mi8 < 8; ++mi8) {
    int m = m0 + wr * 128 + mi8 * 16 + quad * 4;
#pragma unroll
    for (int ni = 0; ni < NI; ++ni) {
      int n = n0 + wc * (BN / 4) + ni * 16 + l16;
      CT* cp = C + (size_t)m * N + n;
#pragma unroll
      for (int r = 0; r < 4; ++r) cp[(size_t)r * N] = (CT)acc[mi8][ni][r];
    }
  }
}

// ---------------- per-head RMSNorm + RoPE, one wave per (s, head) ----------
// raw: [S, row_stride] f16, head block at col_off + h*128 -> out [nh][S][128]
__global__ void norm_rope(const _Float16* __restrict__ raw, int row_stride,
                          int col_off, const float* __restrict__ w,
                          const float* __restrict__ cosb,
                          const float* __restrict__ sinb,
                          const int* __restrict__ pos,
                          _Float16* __restrict__ out, int nh_log2, int S) {
  int gt = blockIdx.x * blockDim.x + threadIdx.x;
  int wid = gt >> 6, lane = gt & 63;
  int h = wid & ((1 << nh_log2) - 1);
  int s = wid >> nh_log2;
  const _Float16* x = raw + (size_t)s * row_stride + col_off + h * 128;
  f16x2 v2 = *(const f16x2*)&x[lane * 2];
  float vx = (float)v2.x, vy = (float)v2.y;
  float ss = vx * vx + vy * vy;
#pragma unroll
  for (int m = 1; m < 64; m <<= 1) ss += __shfl_xor(ss, m);
  float inv = rsqrtf(ss * (1.f / 128.f) + 1e-6f);
  int p = pos[s];
  float n0 = vx * inv * w[lane * 2];
  float n1 = vy * inv * w[lane * 2 + 1];
  float p0 = __shfl_xor(n0, 32);
  float p1 = __shfl_xor(n1, 32);
  float r0 = (lane < 32) ? -p0 : p0;
  float r1 = (lane < 32) ? -p1 : p1;
  float c0 = cosb[p * 128 + lane * 2], c1 = cosb[p * 128 + lane * 2 + 1];
  float s0 = sinb[p * 128 + lane * 2], s1 = sinb[p * 128 + lane * 2 + 1];
  f16x2 o;
  o.x = (_Float16)(n0 * c0 + r0 * s0);
  o.y = (_Float16)(n1 * c1 + r1 * s1);
  *(f16x2*)&out[((size_t)h * S + s) * 128 + lane * 2] = o;
}

// ---------------- V transpose: [S,*] f16 cols -> [1024][S] f16 -------------
__global__ __launch_bounds__(256) void v_trans(const _Float16* __restrict__ vraw,
                                               int row_stride,
                                               _Float16* __restrict__ vt,
                                               int S) {
  __shared__ _Float16 tile[64][72];
  int s0 = blockIdx.x * 64, c0 = blockIdx.y * 64;
  int t = threadIdx.x;
  int r = t >> 2, cq = (t & 3) * 16;
  const _Float16* src = vraw + (size_t)(s0 + r) * row_stride + c0 + cq;
  f16x8 u0 = *(const f16x8*)&src[0];
  f16x8 u1 = *(const f16x8*)&src[8];
#pragma unroll
  for (int j = 0; j < 8; j++) {
    tile[r][cq + j] = u0[j];
    tile[r][cq + 8 + j] = u1[j];
  }
  __syncthreads();
  int orow = t >> 2, sq = (t & 3) * 16;
  _Float16* dst = vt + (size_t)(c0 + orow) * S + s0 + sq;
  f16x8 a, b;
#pragma unroll
  for (int j = 0; j < 8; j++) a[j] = tile[sq + j][orow];
#pragma unroll
  for (int j = 0; j < 8; j++) b[j] = tile[sq + 8 + j][orow];
  *(f16x8*)&dst[0] = a;
  *(f16x8*)&dst[8] = b;
}

// ---------------- causal GQA flash attention (fixed-M softmax) -------------
// Qh: [32][S][128] f16, Kh: [8][S][128] f16, Vt: [8][128][S] f16
// Oout: [S][4096] f16.
// Block = 4 waves; wave = 16 q rows; block handles q-tile pair (px, 31-px)
// of 64 rows each -> uniform 68 kt-iterations per block. K/V tiles staged
// cooperatively into LDS via global_load_lds (linear dest, inverse-swizzled
// global source); reads use the same XOR swizzle.
// R5: 3-deep buffer rotation + counted vmcnt: iter kt issues stage(kt+2),
// computes kt, waits vmcnt(4) (own kt+1 loads landed; kt+2 in flight),
// barrier. Never a full drain in steady state.
__global__ __launch_bounds__(256, 2) void flash_attn(
    const _Float16* __restrict__ Qh, const _Float16* __restrict__ Kh,
    const _Float16* __restrict__ Vt, _Float16* __restrict__ Oout, int S) {
  __shared__ _Float16 lK[3][32 * 128];
  __shared__ _Float16 lV[3][128 * 32];
  __shared__ _Float16 plds[4][16][40];
  const int wave = threadIdx.x >> 6, lane = threadIdx.x & 63;
  const int quad = lane >> 4, l16 = lane & 15;

  const int flat = blockIdx.y * gridDim.x + blockIdx.x;  // 0..511
  const int head = (flat & 7) * 4 + ((flat >> 3) & 3);
  const int px   = flat >> 5;  // 0..15 pair index
  const int kvh  = head >> 2;
  const _Float16* K = Kh + (size_t)kvh * S * 128;
  const _Float16* V = Vt + (size_t)kvh * 128 * S;

  const int ksw = l16 & 7;
  const int vchunk = quad ^ ((l16 >> 1) & 3);
  const float scale = 0.08838834764831845f;  // 1/sqrt(128)
  const float Mc = 5.0f;

  // stage K/V tile kt into buffer bi: 4 gld_lds per thread (vmcnt += 4)
  auto stage = [&](int kt, int bi) {
#pragma unroll
    for (int u = 0; u < 2; ++u) {
      int j = wave * 2 + u;
      int rK = j * 4 + (lane >> 4);
      int cK = (lane & 15) ^ (rK & 7);
      gld_lds16(K + (size_t)(kt * 32 + rK) * 128 + cK * 8, &lK[bi][j * 512]);
      int rV = j * 16 + (lane >> 2);
      int cV = (lane & 3) ^ ((rV >> 1) & 3);
      gld_lds16(V + (size_t)rV * S + kt * 32 + cV * 8, &lV[bi][j * 512]);
    }
  };

#pragma unroll
  for (int seg = 0; seg < 2; ++seg) {
    const int tile = seg ? (31 - px) : px;
    const int q0 = tile * 64;
    const int wq = q0 + wave * 16;
    const _Float16* Q = Qh + ((size_t)head * S + wq) * 128;

    f16x8 qf[4];
#pragma unroll
    for (int kq = 0; kq < 4; kq++)
      qf[kq] = *(const f16x8*)&Q[(size_t)l16 * 128 + kq * 32 + quad * 8];

    f32x4 o[8];
#pragma unroll
    for (int t = 0; t < 8; t++) o[t] = f32x4{0.f, 0.f, 0.f, 0.f};
    float l_i = 0.f;
    const int q_row = wq + l16;
    const int ktend = 2 * tile + 1;  // >= 1 always

    // prologue: kt0 -> buf0, kt1 -> buf1; wait kt0 (oldest 4), kt1 in flight
    stage(0, 0);
    stage(1, 1);
    WAIT_VMCNT(4);
    barrier_raw();

    for (int kt = 0; kt <= ktend; ++kt) {
      const int cur = kt % 3;
      const bool more = (kt + 2 <= ktend);  // block-uniform
      if (more) stage(kt + 2, (kt + 2) % 3);
      if (kt * 32 <= wq + 15) {  // wave-uniform skip of fully-masked tiles
        f32x4 sc[2];
        sc[0] = f32x4{0.f, 0.f, 0.f, 0.f};
        sc[1] = f32x4{0.f, 0.f, 0.f, 0.f};
#pragma unroll
        for (int mt = 0; mt < 2; mt++)
#pragma unroll
          for (int kq = 0; kq < 4; kq++) {
            f16x8 kf = *(const f16x8*)&lK[cur][(mt * 16 + l16) * 128 +
                                              (((kq * 4 + quad) ^ ksw) * 8)];
            sc[mt] = __builtin_amdgcn_mfma_f32_16x16x32_f16(kf, qf[kq], sc[mt],
                                                            0, 0, 0);
          }
        float p[2][4];
        float rsum = 0.f;
#pragma unroll
        for (int mt = 0; mt < 2; mt++)
#pragma unroll
          for (int r = 0; r < 4; r++) {
            int kcol = kt * 32 + mt * 16 + quad * 4 + r;
            float e = __expf(fmaf(sc[mt][r], scale, -Mc));
            e = (kcol <= q_row) ? e : 0.f;
            p[mt][r] = e;
            rsum += e;
          }
        rsum += __shfl_xor(rsum, 16);
        rsum += __shfl_xor(rsum, 32);
        l_i += rsum;
        f16x4 pk0 = {(_Float16)p[0][0], (_Float16)p[0][1], (_Float16)p[0][2],
                     (_Float16)p[0][3]};
        f16x4 pk1 = {(_Float16)p[1][0], (_Float16)p[1][1], (_Float16)p[1][2],
                     (_Float16)p[1][3]};
        *(f16x4*)&plds[wave][l16][quad * 4] = pk0;
        *(f16x4*)&plds[wave][l16][16 + quad * 4] = pk1;
        f16x8 pf = *(const f16x8*)&plds[wave][l16][quad * 8];
#pragma unroll
        for (int t = 0; t < 8; t++) {
          f16x8 vf = *(const f16x8*)&lV[cur][(t * 16 + l16) * 32 + vchunk * 8];
          o[t] = __builtin_amdgcn_mfma_f32_16x16x32_f16(vf, pf, o[t], 0, 0, 0);
        }
      }
      // own kt+1 loads landed (kt+2 still flying); all waves past barrier =>
      // whole kt+1 buffer valid next iter
      if (more) {
        WAIT_VMCNT(4);
      } else {
        WAIT_VMCNT(0);
      }
      barrier_raw();
    }

    const float invl = 1.f / l_i;
    _Float16* op = Oout + (size_t)q_row * 4096 + head * 128 + quad * 4;
#pragma unroll
    for (int t = 0; t < 8; t++) {
      f16x4 ov = {(_Float16)(o[t][0] * invl), (_Float16)(o[t][1] * invl),
                  (_Float16)(o[t][2] * invl), (_Float16)(o[t][3] * invl)};
      *(f16x4*)&op[t * 16] = ov;
    }
  }
}

// ---------------------------------------------------------------------------
extern "C" void kernel_launch(void* const* d_in, const int* in_sizes, int n_in,
                              void* d_out, int out_size, void* d_ws,
                              size_t ws_size, hipStream_t stream) {
  const int S = 2048, H = 4096, NH = 32, NKV = 8, D = 128;
  const int NQKV = NH * D + 2 * NKV * D;  // 6144
  const float* hs   = (const float*)d_in[0];
  const int*   pos  = (const int*)d_in[1];
  const float* Wq   = (const float*)d_in[2];
  const float* Wk   = (const float*)d_in[3];
  const float* Wv   = (const float*)d_in[4];
  const float* Wo   = (const float*)d_in[5];
  const float* qw   = (const float*)d_in[6];
  const float* kw   = (const float*)d_in[7];
  const float* cosb = (const float*)d_in[8];
  const float* sinb = (const float*)d_in[9];
  float* out = (float*)d_out;

  // workspace layout (bytes); total 142,606,336
  char* ws = (char*)d_ws;
  _Float16* wqkv    = (_Float16*)(ws + 0);          // 50.33 MB [6144][4096]
  _Float16* hid_bf  = (_Float16*)(ws + 50331648);   // 16.78 MB [S][H]
  _Float16* qkv_f16 = (_Float16*)(ws + 67108864);   // 25.17 MB [S][6144] f16
  _Float16* q_bf    = (_Float16*)(ws + 117440512);  // 16.78 MB [32][S][128]
  _Float16* k_bf    = (_Float16*)(ws + 134217728);  //  4.19 MB [8][S][128]
  _Float16* v_t     = (_Float16*)(ws + 138412032);  //  4.19 MB [1024][S]
  _Float16* attn_bf = (_Float16*)(ws + 96468992);   // 16.78 MB (scratch gap)
  _Float16* wo_bf   = (_Float16*)(ws + 0);          // alias wqkv (dead)

  // fused fp32 -> f16 converts: hs -> hid_bf, Wq/Wk/Wv -> wqkv
  const int n_hs4 = S * H / 4;              // 2,097,152
  const int n_wq4 = NH * D * H / 4;         // 4,194,304
  const int n_wk4 = NKV * D * H / 4;        // 1,048,576
  const int n_wv4 = NKV * D * H / 4;        // 1,048,576
  const int ncvt = n_hs4 + n_wq4 + n_wk4 + n_wv4;
  cvt4<<<(ncvt + 255) / 256, 256, 0, stream>>>(
      hs, Wq, Wk, Wv, hid_bf, wqkv, wqkv + (size_t)H * H,
      wqkv + (size_t)(H + NKV * D) * H, n_hs4, n_wq4, n_wk4, n_wv4);

  // fused QKV projection: [2048][6144] f16 = hid @ wqkv^T  (8-phase, BN=256)
  gemm256<256, _Float16><<<dim3((NQKV / 256) * 8), 512, 0, stream>>>(
      hid_bf, wqkv, qkv_f16, NQKV, H);
  // Wo convert into wqkv slot (dead after QKV gemm)
  f32_to_f16<<<(H * H / 4 + 255) / 256, 256, 0, stream>>>(Wo, wo_bf, H * H / 4);

  // per-head RMSNorm + RoPE (f16 input)
  norm_rope<<<S * NH / 4, 256, 0, stream>>>(qkv_f16, NQKV, 0, qw, cosb, sinb,
                                            pos, q_bf, 5, S);
  norm_rope<<<S * NKV / 4, 256, 0, stream>>>(qkv_f16, NQKV, H, kw, cosb, sinb,
                                             pos, k_bf, 3, S);
  v_trans<<<dim3(S / 64, NKV * D / 64), 256, 0, stream>>>(
      qkv_f16 + (size_t)(H + NKV * D), NQKV, v_t, S);

  // causal flash attention -> attn_bf [S][4096] f16
  flash_attn<<<dim3(16, NH), 256, 0, stream>>>(q_bf, k_bf, v_t, attn_bf, S);

  // output projection -> d_out fp32  (8-phase, BN=128: 256 blocks, full chip)
  gemm256<128, float><<<dim3((H / 128) * 8), 512, 0, stream>>>(attn_bf, wo_bf,
                                                               out, H, H);
}